// Round 17
// baseline (282.509 us; speedup 1.0000x reference)
//
#include <hip/hip_runtime.h>

#define B_ 2
#define T_ 2048
#define C_ 2048
#define NH_ 16
#define NKV_ 4
#define HD_ 128
#define M_ 4096          // B*T
#define NQKV_ 3072

typedef __bf16 bf16x8 __attribute__((ext_vector_type(8)));
typedef float f32x4 __attribute__((ext_vector_type(4)));
typedef float f32x16 __attribute__((ext_vector_type(16)));

__device__ __forceinline__ unsigned short f2bf(float f) {
  union { float f; unsigned u; } c{f};
  unsigned u = c.u + 0x7FFFu + ((c.u >> 16) & 1u);
  return (unsigned short)(u >> 16);
}
__device__ __forceinline__ float bf2f(unsigned short h) {
  union { unsigned u; float f; } c{(unsigned)h << 16};
  return c.f;
}

#define GLOAD_LDS16(g, l)                                        \
  __builtin_amdgcn_global_load_lds(                              \
      (const __attribute__((address_space(1))) void*)(g),        \
      (__attribute__((address_space(3))) void*)(l), 16, 0, 0)

// asm ds_read_b128 (rule #18: fence with lgkmcnt(0)+sched_barrier(0) before use)
__device__ __forceinline__ bf16x8 ldsread128(const unsigned short* p) {
  uint4 d;
  asm volatile("ds_read_b128 %0, %1"
               : "=v"(d)
               : "v"((const __attribute__((address_space(3))) void*)p));
  union { uint4 u; bf16x8 v; } c;
  c.u = d;
  return c.v;
}

// ---------------- fused prep: weight transposes + x->bf16 + rope table
__global__ void prep_kernel(const float* __restrict__ x, const float* __restrict__ Wq,
                            const float* __restrict__ Wk, const float* __restrict__ Wv,
                            const float* __restrict__ Wp, unsigned short* __restrict__ xb,
                            unsigned short* __restrict__ wt, float2* __restrict__ rt) {
  int id = blockIdx.x;
  if (id < 10240) {  // weight transpose-convert
    __shared__ float tile[32][33];
    const float* W;
    unsigned short* Wt;
    int N, bx, by;
    if (id < 4096)      { W = Wq; Wt = wt;                       N = 2048; int u = id;        bx = u & 63; by = u >> 6; }
    else if (id < 5120) { W = Wk; Wt = wt + (size_t)2048 * 2048; N = 512;  int u = id - 4096; bx = u & 15; by = u >> 4; }
    else if (id < 6144) { W = Wv; Wt = wt + (size_t)2560 * 2048; N = 512;  int u = id - 5120; bx = u & 15; by = u >> 4; }
    else                { W = Wp; Wt = wt + (size_t)3072 * 2048; N = 2048; int u = id - 6144; bx = u & 63; by = u >> 6; }
    const int K = 2048;
    bx *= 32; by *= 32;
    int tx = threadIdx.x & 31, ty = threadIdx.x >> 5;
#pragma unroll
    for (int r = 0; r < 32; r += 8)
      tile[ty + r][tx] = W[(size_t)(by + ty + r) * N + bx + tx];
    __syncthreads();
#pragma unroll
    for (int r = 0; r < 32; r += 8)
      Wt[(size_t)(bx + ty + r) * K + by + tx] = f2bf(tile[tx][ty + r]);
  } else if (id < 18432) {  // x f32 -> bf16, float4 chunks
    int i = (id - 10240) * 256 + threadIdx.x;
    float4 v = reinterpret_cast<const float4*>(x)[i];
    union { ushort4 u; unsigned short s[4]; } o;
    o.s[0] = f2bf(v.x); o.s[1] = f2bf(v.y); o.s[2] = f2bf(v.z); o.s[3] = f2bf(v.w);
    reinterpret_cast<ushort4*>(xb)[i] = o.u;
  } else {  // rope table
    int g = (id - 18432) * 256 + threadIdx.x;
    int t = g >> 6, i = g & 63;
    float inv = powf(10000.f, -(float)(2 * i) / 128.f);
    float s, c;
    sincosf((float)t * inv, &s, &c);
    rt[t * 64 + i] = make_float2(c, s);
  }
}

// ---------------- V slice of qkv -> vt[(b*NKV+kvh)*HD + d][t]  (bf16 transpose)
__global__ void transpose_v_kernel(const unsigned short* __restrict__ qkv,
                                   unsigned short* __restrict__ vt) {
  __shared__ unsigned short tile[32][33];
  int bh = blockIdx.z;                 // b*NKV + kvh
  int b = bh >> 2, kvh = bh & 3;
  int t0 = blockIdx.x * 32, d0 = blockIdx.y * 32;
  int tx = threadIdx.x & 31, ty = threadIdx.x >> 5;
#pragma unroll
  for (int r = 0; r < 32; r += 8)
    tile[ty + r][tx] = qkv[(size_t)(b * T_ + t0 + ty + r) * NQKV_ + 2560 + kvh * HD_ + d0 + tx];
  __syncthreads();
#pragma unroll
  for (int r = 0; r < 32; r += 8)
    vt[(size_t)(bh * HD_ + d0 + ty + r) * T_ + t0 + tx] = tile[tx][ty + r];
}

// ---------------- 8-phase bf16 GEMM (T3+T4+T5), asm ds_read (R14, proven)
template <int BM, typename OUT, bool ROPE>
__global__ __launch_bounds__(512, 1) void gemm8p(const unsigned short* __restrict__ A,
                                                 const unsigned short* __restrict__ Bt,
                                                 OUT* __restrict__ Cm,
                                                 const float2* __restrict__ rt,
                                                 int M, int N, int K) {
  constexpr int MR = BM / 64;
  __shared__ __align__(16) unsigned short As[2][2][BM * 32];
  __shared__ __align__(16) unsigned short Bs[2][2][256 * 32];
  int tid = threadIdx.x, wid = tid >> 6, lane = tid & 63;
  int l15 = lane & 15, l4 = lane >> 4;
  int wr = wid >> 1, wc = wid & 1;
  size_t arow0 = (size_t)blockIdx.y * BM;
  size_t brow0 = (size_t)blockIdx.x * 256;
  int tmax = K / 64 - 1;

  f32x4 acc[MR][8];
#pragma unroll
  for (int m = 0; m < MR; ++m)
#pragma unroll
    for (int n = 0; n < 8; ++n) acc[m][n] = (f32x4){0.f, 0.f, 0.f, 0.f};

  auto stageA = [&](int slot, int kh, int tile) {
    int k0 = tile * 64 + kh * 32;
    constexpr int NLD = (BM * 32 * 2) / (512 * 16);
#pragma unroll
    for (int i = 0; i < NLD; ++i) {
      int c = i * 512 + wid * 64 + lane;
      int rg = c >> 2, cg = (c & 3) ^ (rg & 3);
      const unsigned short* g = A + (arow0 + rg) * K + k0 + cg * 8;
      GLOAD_LDS16(g, &As[slot][kh][c * 8]);
    }
  };
  auto stageB = [&](int slot, int kh, int tile) {
    int k0 = tile * 64 + kh * 32;
#pragma unroll
    for (int i = 0; i < 2; ++i) {
      int c = i * 512 + wid * 64 + lane;
      int rg = c >> 2, cg = (c & 3) ^ (rg & 3);
      const unsigned short* g = Bt + (brow0 + rg) * K + k0 + cg * 8;
      GLOAD_LDS16(g, &Bs[slot][kh][c * 8]);
    }
  };

  stageA(0, 0, 0); stageB(0, 0, 0); stageA(0, 1, 0); stageB(0, 1, 0);
  stageA(1, 0, 1); stageB(1, 0, 1); stageA(1, 1, 1);
  if constexpr (BM == 256) asm volatile("s_waitcnt vmcnt(6)" ::: "memory");
  else                     asm volatile("s_waitcnt vmcnt(4)" ::: "memory");
  __builtin_amdgcn_s_barrier();

  int NT2 = K / 128;
  for (int it = 0; it < NT2; ++it) {
    int t2 = it * 2;
#pragma unroll
    for (int tt = 0; tt < 2; ++tt) {
      bf16x8 af[MR];
#pragma unroll
      for (int kh = 0; kh < 2; ++kh) {
#pragma unroll
        for (int nh = 0; nh < 2; ++nh) {
          int p = tt * 4 + kh * 2 + nh + 1;
          if (nh == 0) {
#pragma unroll
            for (int m = 0; m < MR; ++m) {
              int r = wr * (MR * 16) + m * 16 + l15;
              af[m] = ldsread128(&As[tt][kh][r * 32 + ((l4 ^ (r & 3)) * 8)]);
            }
          }
          bf16x8 bf[4];
#pragma unroll
          for (int j = 0; j < 4; ++j) {
            int r = wc * 128 + (nh * 4 + j) * 16 + l15;
            bf[j] = ldsread128(&Bs[tt][kh][r * 32 + ((l4 ^ (r & 3)) * 8)]);
          }
          if (p == 1) stageB(1, 1, t2 + 1);
          if (p == 2) stageA(0, 0, t2 + 2 <= tmax ? t2 + 2 : tmax);
          if (p == 3) stageB(0, 0, t2 + 2 <= tmax ? t2 + 2 : tmax);
          if (p == 4) stageA(0, 1, t2 + 2 <= tmax ? t2 + 2 : tmax);
          if (p == 5) stageB(0, 1, t2 + 2 <= tmax ? t2 + 2 : tmax);
          if (p == 6) stageA(1, 0, t2 + 3 <= tmax ? t2 + 3 : tmax);
          if (p == 7) stageB(1, 0, t2 + 3 <= tmax ? t2 + 3 : tmax);
          if (p == 8) stageA(1, 1, t2 + 3 <= tmax ? t2 + 3 : tmax);

          __builtin_amdgcn_s_barrier();
          asm volatile("s_waitcnt lgkmcnt(0)" ::: "memory");
          __builtin_amdgcn_sched_barrier(0);
          __builtin_amdgcn_s_setprio(1);
#pragma unroll
          for (int m = 0; m < MR; ++m)
#pragma unroll
            for (int j = 0; j < 4; ++j)
              acc[m][nh * 4 + j] = __builtin_amdgcn_mfma_f32_16x16x32_bf16(
                  af[m], bf[j], acc[m][nh * 4 + j], 0, 0, 0);
          __builtin_amdgcn_s_setprio(0);
          if (p == 4 || p == 8) {
            if constexpr (BM == 256) asm volatile("s_waitcnt vmcnt(6)" ::: "memory");
            else                     asm volatile("s_waitcnt vmcnt(4)" ::: "memory");
          }
          __builtin_amdgcn_s_barrier();
        }
      }
    }
  }

  bool dorope = ROPE && (brow0 + wc * 128 < 2560);
#pragma unroll
  for (int m = 0; m < MR; ++m)
#pragma unroll
    for (int r = 0; r < 4; ++r) {
      size_t row = arow0 + wr * (MR * 16) + m * 16 + l4 * 4 + r;
      if (dorope) {
        int t = (int)(row & (T_ - 1));
#pragma unroll
        for (int n = 0; n < 4; ++n) {
          float2 cs = rt[t * 64 + n * 16 + l15];
          float a1 = acc[m][n][r], a2 = acc[m][n + 4][r];
          size_t col = brow0 + wc * 128 + n * 16 + l15;
          Cm[row * N + col]      = f2bf(a1 * cs.x - a2 * cs.y);
          Cm[row * N + col + 64] = f2bf(a2 * cs.x + a1 * cs.y);
        }
      } else {
#pragma unroll
        for (int n = 0; n < 8; ++n) {
          size_t col = brow0 + wc * 128 + n * 16 + l15;
          float v = acc[m][n][r];
          if constexpr (sizeof(OUT) == 4) Cm[row * N + col] = v;
          else                            Cm[row * N + col] = f2bf(v);
        }
      }
    }
}

// ---------------- flash attention: R15 KV-split LPT + single-buffer V via
// T14 reg-staging. LDS = Kl dbuf (32KB) + Vl single (16KB) = 48KB -> 3
// blocks/CU. Per iter: issue V(t+1)->regs + K(t+1)->Kl (async) | QK(t) |
// softmax | ds_write V(t) | raw s_barrier+lgkmcnt(0) (NO vmcnt drain) |
// PV(t) | __syncthreads (drains prefetch). No forced min-occupancy (R9 spill).
__global__ __launch_bounds__(256) void attn_kernel(const unsigned short* __restrict__ qkv,
                                                   const unsigned short* __restrict__ vt,
                                                   unsigned short* __restrict__ att,
                                                   unsigned short* __restrict__ pO,
                                                   float2* __restrict__ ml) {
  constexpr int KB = 64;
  __shared__ __align__(16) unsigned short Kl[2][KB * 128];   // 32KB, swizzled
  __shared__ __align__(16) unsigned short Vl[128 * KB];      // 16KB, swizzled
  int tid = threadIdx.x, w = tid >> 6, lane = tid & 63;
  int l31 = lane & 31, hi = lane >> 5;
  int h4 = hi * 4;

  // LPT decode
  int id = blockIdx.x;
  int qi, bh, kt0, kt1, slot = -1;
  if (id < 64) {                       // unsplit qi 9,8 (longest items first)
    qi = 9 - (id >> 5); bh = id & 31; kt0 = 0; kt1 = 2 * qi + 2;
  } else if (id < 448) {               // split qi 15..10, two KV halves
    int s = id - 64;
    int pairidx = s >> 1, hihalf = s & 1;
    qi = 15 - (pairidx >> 5); bh = pairidx & 31;
    int nt = 2 * qi + 2, h = nt >> 1;
    kt0 = hihalf ? h : 0; kt1 = hihalf ? nt : h;
    slot = s;
  } else {                             // unsplit qi 7..0
    int u = id - 448;
    qi = 7 - (u >> 5); bh = u & 31; kt0 = 0; kt1 = 2 * qi + 2;
  }
  int q0 = qi * 128;
  int b = bh >> 4, hd = bh & 15, kvh = hd >> 2;
  int qr0 = q0 + w * 32;
  int ql = qr0 + l31;

  bf16x8 qf[8];
  {
    const unsigned short* qb = qkv + (size_t)(b * T_ + ql) * NQKV_ + hd * HD_ + hi * 8;
    const float scale = 0.08838834764831845f * 1.4426950408889634f;
#pragma unroll
    for (int df = 0; df < 8; ++df) {
      bf16x8 t = *reinterpret_cast<const bf16x8*>(qb + df * 16);
#pragma unroll
      for (int j = 0; j < 8; ++j) t[j] = (__bf16)((float)t[j] * scale);
      qf[df] = t;
    }
  }

  f32x16 o[4];
#pragma unroll
  for (int dt = 0; dt < 4; ++dt)
#pragma unroll
    for (int r = 0; r < 16; ++r) o[dt][r] = 0.f;
  float mr = -1e30f, lr = 0.f;

  auto stage_K = [&](int buf, int tile) {
    int kv0 = tile * KB;
#pragma unroll
    for (int i = 0; i < 4; ++i) {  // chunk c ^= (row&7), row = c>>4
      int c = (i * 4 + w) * 64 + lane;
      int g = c ^ ((c >> 4) & 7);
      const unsigned short* src =
          qkv + (size_t)(b * T_ + kv0 + (g >> 4)) * NQKV_ + C_ + kvh * HD_ + (g & 15) * 8;
      GLOAD_LDS16(src, &Kl[buf][(i * 4 + w) * 512]);
    }
  };

  // V reg-staging: wave w owns d rows [w*32, w*32+32); lane chunk i:
  // d = w*32 + i*8 + (lane>>3), kv granule = lane&7 (swizzled slot kv8^(d&7))
  uint4 vreg[4];
  const unsigned short* vbase = vt + (size_t)((b * NKV_ + kvh) * HD_) * T_;
  auto load_V = [&](int tile) {
    int kv0 = tile * KB;
#pragma unroll
    for (int i = 0; i < 4; ++i) {
      int d = w * 32 + i * 8 + (lane >> 3);
      vreg[i] = *reinterpret_cast<const uint4*>(vbase + (size_t)d * T_ + kv0 + (lane & 7) * 8);
    }
  };
  auto write_V = [&]() {
#pragma unroll
    for (int i = 0; i < 4; ++i) {
      int d = w * 32 + i * 8 + (lane >> 3);
      int kv8 = lane & 7;
      *reinterpret_cast<uint4*>(&Vl[d * 64 + ((kv8 ^ (d & 7)) << 3)]) = vreg[i];
    }
  };

  // prologue: K(kt0)->LDS, V(kt0)->regs; drain both
  stage_K(0, kt0);
  load_V(kt0);
  __syncthreads();

  int cur = 0;
  for (int kt = kt0; kt < kt1; ++kt) {
    int kv0 = kt * KB;
    int tn = kt + 1 < kt1 ? kt + 1 : kt1 - 1;  // tail clamp
    stage_K(cur ^ 1, tn);                      // async K(t+1)

    bool active = (kv0 <= qr0 + 31);
    unsigned pk[2][8];
    if (active) {
      f32x16 s[2];
#pragma unroll
      for (int r = 0; r < 16; ++r) { s[0][r] = 0.f; s[1][r] = 0.f; }
      const unsigned short* Kb = &Kl[cur][0];
      __builtin_amdgcn_s_setprio(1);
#pragma unroll
      for (int t2 = 0; t2 < 2; ++t2)
#pragma unroll
        for (int df = 0; df < 8; ++df) {
          bf16x8 kf = *reinterpret_cast<const bf16x8*>(
              Kb + (((t2 * 32 + l31) * 128 + df * 16 + hi * 8) ^ ((l31 & 7) << 3)));
          s[t2] = __builtin_amdgcn_mfma_f32_32x32x16_bf16(kf, qf[df], s[t2], 0, 0, 0);
        }
      __builtin_amdgcn_s_setprio(0);

      float rm = -1e30f;
      if ((kv0 + KB - 1) > qr0) {
#pragma unroll
        for (int t2 = 0; t2 < 2; ++t2)
#pragma unroll
          for (int r = 0; r < 16; ++r) {
            float sv = s[t2][r];
            int kcol = kv0 + t2 * 32 + (r & 3) + 8 * (r >> 2) + h4;
            if (kcol > ql) sv = -1e30f;
            s[t2][r] = sv;
            rm = fmaxf(rm, sv);
          }
      } else {
#pragma unroll
        for (int t2 = 0; t2 < 2; ++t2)
#pragma unroll
          for (int r = 0; r < 16; ++r) rm = fmaxf(rm, s[t2][r]);
      }
      rm = fmaxf(rm, __shfl_xor(rm, 32));

      if (!__all(rm <= mr + 11.0f)) {
        float mnew = fmaxf(mr, rm);
        float alpha = exp2f(mr - mnew);
        mr = mnew;
        lr *= alpha;
#pragma unroll
        for (int dt = 0; dt < 4; ++dt)
#pragma unroll
          for (int r = 0; r < 16; ++r) o[dt][r] *= alpha;
      }

      float ps = 0.f;
#pragma unroll
      for (int t2 = 0; t2 < 2; ++t2)
#pragma unroll
        for (int r = 0; r < 16; ++r) {
          float p = exp2f(s[t2][r] - mr);
          s[t2][r] = p;
          ps += p;
        }
      lr += ps;

#pragma unroll
      for (int t2 = 0; t2 < 2; ++t2)
#pragma unroll
        for (int i = 0; i < 8; ++i) {
          union { unsigned u32; __bf16 hh[2]; } pr;
          pr.hh[0] = (__bf16)s[t2][2 * i];
          pr.hh[1] = (__bf16)s[t2][2 * i + 1];
          pk[t2][i] = pr.u32;
        }
    }

    // publish V(t) to LDS (vreg drained at the last __syncthreads), then
    // issue V(t+1)->regs; fence ds_writes only (raw barrier, NO vmcnt drain)
    write_V();
    load_V(tn);
    asm volatile("s_waitcnt lgkmcnt(0)" ::: "memory");
    __builtin_amdgcn_s_barrier();
    __builtin_amdgcn_sched_barrier(0);

    if (active) {
      bf16x8 pb[4];
#pragma unroll
      for (int f = 0; f < 4; ++f) {
        int t2 = f >> 1, bq = (f & 1) * 4;
        union { bf16x8 v; unsigned d[4]; } fr;
#pragma unroll
        for (int p = 0; p < 2; ++p) {
          unsigned uu = pk[t2][bq + p];
          unsigned ww = pk[t2][bq + 2 + p];
          unsigned us = (unsigned)__shfl_xor((int)uu, 32);
          unsigned ws = (unsigned)__shfl_xor((int)ww, 32);
          fr.d[p]     = hi ? ws : uu;
          fr.d[2 + p] = hi ? ww : us;
        }
        pb[f] = fr.v;
      }

      __builtin_amdgcn_s_setprio(1);
#pragma unroll
      for (int dt = 0; dt < 4; ++dt)
#pragma unroll
        for (int kf = 0; kf < 4; ++kf) {
          bf16x8 vf = *reinterpret_cast<const bf16x8*>(
              Vl + (((dt * 32 + l31) * KB + kf * 16 + hi * 8) ^ ((l31 & 7) << 3)));
          o[dt] = __builtin_amdgcn_mfma_f32_32x32x16_bf16(vf, pb[kf], o[dt], 0, 0, 0);
        }
      __builtin_amdgcn_s_setprio(0);
    }

    __syncthreads();  // drains K(t+1)+V(t+1); guards Kl/Vl reuse
    cur ^= 1;
  }

  float ls = lr + __shfl_xor(lr, 32);
  if (slot < 0) {
    float inv = 1.f / ls;
    unsigned short* ob = att + (size_t)(b * T_ + ql) * C_ + hd * HD_;
#pragma unroll
    for (int dt = 0; dt < 4; ++dt)
#pragma unroll
      for (int r = 0; r < 16; ++r) {
        int d = dt * 32 + (r & 3) + 8 * (r >> 2) + h4;
        ob[d] = f2bf(o[dt][r] * inv);
      }
  } else {
    int lrow = w * 32 + l31;
    unsigned short* po = pO + (size_t)slot * 16384 + lrow * 128;
#pragma unroll
    for (int dt = 0; dt < 4; ++dt)
#pragma unroll
      for (int r = 0; r < 16; ++r) {
        int d = dt * 32 + (r & 3) + 8 * (r >> 2) + h4;
        po[d] = f2bf(o[dt][r]);
      }
    if (hi == 0) ml[slot * 128 + lrow] = make_float2(mr, ls);
  }
}

// ---------------- merge KV-split halves: O = (w0*O0 + w1*O1) / (w0*l0 + w1*l1)
__global__ void combine_kernel(const unsigned short* __restrict__ pO,
                               const float2* __restrict__ ml,
                               unsigned short* __restrict__ att) {
  int pairidx = blockIdx.x;            // 0..191
  int qi = 15 - (pairidx >> 5), bh = pairidx & 31;
  int b = bh >> 4, hd = bh & 15;
  int q0 = qi * 128;
  int s0 = pairidx * 2, s1 = s0 + 1;
  int tid = threadIdx.x;               // 256: 2 threads per row, 64 d each
  int row = tid >> 1, dh = (tid & 1) * 64;
  float2 ml0 = ml[s0 * 128 + row], ml1 = ml[s1 * 128 + row];
  float m = fmaxf(ml0.x, ml1.x);
  float w0 = exp2f(ml0.x - m), w1 = exp2f(ml1.x - m);
  float inv = 1.f / (w0 * ml0.y + w1 * ml1.y);
  const unsigned short* p0 = pO + (size_t)s0 * 16384 + row * 128 + dh;
  const unsigned short* p1 = pO + (size_t)s1 * 16384 + row * 128 + dh;
  unsigned short* ob = att + (size_t)(b * T_ + q0 + row) * C_ + hd * HD_ + dh;
#pragma unroll
  for (int j = 0; j < 64; j += 4) {
    ushort4 a = *reinterpret_cast<const ushort4*>(p0 + j);
    ushort4 c = *reinterpret_cast<const ushort4*>(p1 + j);
    ushort4 r;
    r.x = f2bf((w0 * bf2f(a.x) + w1 * bf2f(c.x)) * inv);
    r.y = f2bf((w0 * bf2f(a.y) + w1 * bf2f(c.y)) * inv);
    r.z = f2bf((w0 * bf2f(a.z) + w1 * bf2f(c.z)) * inv);
    r.w = f2bf((w0 * bf2f(a.w) + w1 * bf2f(c.w)) * inv);
    *reinterpret_cast<ushort4*>(ob + j) = r;
  }
}

extern "C" void kernel_launch(void* const* d_in, const int* in_sizes, int n_in,
                              void* d_out, int out_size, void* d_ws, size_t ws_size,
                              hipStream_t stream) {
  const float* x  = (const float*)d_in[0];
  const float* Wq = (const float*)d_in[1];
  const float* Wk = (const float*)d_in[2];
  const float* Wv = (const float*)d_in[3];
  const float* Wp = (const float*)d_in[4];
  float* out = (float*)d_out;
  char* ws = (char*)d_ws;

  // workspace layout (bytes); total 68,157,440
  unsigned short* xb  = (unsigned short*)(ws);              // 16MB  x bf16 (att aliases)
  unsigned short* wt  = (unsigned short*)(ws + 16777216);   // 20MB  Wq^T|Wk^T|Wv^T|Wp^T
  unsigned short* qkv = (unsigned short*)(ws + 37748736);   // 24MB  q(rope)|k(rope)|v
  float2*         rt  = (float2*)(ws + 62914560);           // 1MB   cos/sin (dead after GEMM1)
  unsigned short* vt  = (unsigned short*)(ws + 63963136);   // 4MB   V d-major [bh*HD+d][t]
  unsigned short* att = xb;                                 // alias: xb dead after GEMM1
  unsigned short* pO  = wt;                                 // alias: Wq/k/v^T dead after GEMM1
  float2*         ml  = rt;                                 // alias: rt dead after GEMM1

  prep_kernel<<<dim3(18944), 256, 0, stream>>>(x, Wq, Wk, Wv, Wp, xb, wt, rt);

  gemm8p<256, unsigned short, true><<<dim3(NQKV_ / 256, M_ / 256), 512, 0, stream>>>(
      xb, wt, qkv, rt, M_, NQKV_, C_);
  transpose_v_kernel<<<dim3(T_ / 32, HD_ / 32, B_ * NKV_), 256, 0, stream>>>(qkv, vt);
  attn_kernel<<<dim3(704), 256, 0, stream>>>(qkv, vt, att, pO, ml);
  combine_kernel<<<dim3(192), 256, 0, stream>>>(pO, ml, att);
  gemm8p<128, float, false><<<dim3(C_ / 256, M_ / 128), 512, 0, stream>>>(
      att, wt + (size_t)3072 * 2048, out, nullptr, M_, C_, C_);
}

// Round 18
// 216.904 us; speedup vs baseline: 1.3025x; 1.3025x over previous
//
#include <hip/hip_runtime.h>

#define B_ 2
#define T_ 2048
#define C_ 2048
#define NH_ 16
#define NKV_ 4
#define HD_ 128
#define M_ 4096          // B*T
#define NQKV_ 3072

typedef __bf16 bf16x8 __attribute__((ext_vector_type(8)));
typedef float f32x4 __attribute__((ext_vector_type(4)));
typedef float f32x16 __attribute__((ext_vector_type(16)));

__device__ __forceinline__ unsigned short f2bf(float f) {
  union { float f; unsigned u; } c{f};
  unsigned u = c.u + 0x7FFFu + ((c.u >> 16) & 1u);
  return (unsigned short)(u >> 16);
}
__device__ __forceinline__ float bf2f(unsigned short h) {
  union { unsigned u; float f; } c{(unsigned)h << 16};
  return c.f;
}

#define GLOAD_LDS16(g, l)                                        \
  __builtin_amdgcn_global_load_lds(                              \
      (const __attribute__((address_space(1))) void*)(g),        \
      (__attribute__((address_space(3))) void*)(l), 16, 0, 0)

// asm ds_read_b128 (rule #18: fence with lgkmcnt(0)+sched_barrier(0) before use)
__device__ __forceinline__ bf16x8 ldsread128(const unsigned short* p) {
  uint4 d;
  asm volatile("ds_read_b128 %0, %1"
               : "=v"(d)
               : "v"((const __attribute__((address_space(3))) void*)p));
  union { uint4 u; bf16x8 v; } c;
  c.u = d;
  return c.v;
}

// ---------------- fused prep: weight transposes + x->bf16 + rope table
__global__ void prep_kernel(const float* __restrict__ x, const float* __restrict__ Wq,
                            const float* __restrict__ Wk, const float* __restrict__ Wv,
                            const float* __restrict__ Wp, unsigned short* __restrict__ xb,
                            unsigned short* __restrict__ wt, float2* __restrict__ rt) {
  int id = blockIdx.x;
  if (id < 10240) {  // weight transpose-convert
    __shared__ float tile[32][33];
    const float* W;
    unsigned short* Wt;
    int N, bx, by;
    if (id < 4096)      { W = Wq; Wt = wt;                       N = 2048; int u = id;        bx = u & 63; by = u >> 6; }
    else if (id < 5120) { W = Wk; Wt = wt + (size_t)2048 * 2048; N = 512;  int u = id - 4096; bx = u & 15; by = u >> 4; }
    else if (id < 6144) { W = Wv; Wt = wt + (size_t)2560 * 2048; N = 512;  int u = id - 5120; bx = u & 15; by = u >> 4; }
    else                { W = Wp; Wt = wt + (size_t)3072 * 2048; N = 2048; int u = id - 6144; bx = u & 63; by = u >> 6; }
    const int K = 2048;
    bx *= 32; by *= 32;
    int tx = threadIdx.x & 31, ty = threadIdx.x >> 5;
#pragma unroll
    for (int r = 0; r < 32; r += 8)
      tile[ty + r][tx] = W[(size_t)(by + ty + r) * N + bx + tx];
    __syncthreads();
#pragma unroll
    for (int r = 0; r < 32; r += 8)
      Wt[(size_t)(bx + ty + r) * K + by + tx] = f2bf(tile[tx][ty + r]);
  } else if (id < 18432) {  // x f32 -> bf16, float4 chunks
    int i = (id - 10240) * 256 + threadIdx.x;
    float4 v = reinterpret_cast<const float4*>(x)[i];
    union { ushort4 u; unsigned short s[4]; } o;
    o.s[0] = f2bf(v.x); o.s[1] = f2bf(v.y); o.s[2] = f2bf(v.z); o.s[3] = f2bf(v.w);
    reinterpret_cast<ushort4*>(xb)[i] = o.u;
  } else {  // rope table
    int g = (id - 18432) * 256 + threadIdx.x;
    int t = g >> 6, i = g & 63;
    float inv = powf(10000.f, -(float)(2 * i) / 128.f);
    float s, c;
    sincosf((float)t * inv, &s, &c);
    rt[t * 64 + i] = make_float2(c, s);
  }
}

// ---------------- V slice of qkv -> vt[(b*NKV+kvh)*HD + d][t]  (bf16 transpose)
__global__ void transpose_v_kernel(const unsigned short* __restrict__ qkv,
                                   unsigned short* __restrict__ vt) {
  __shared__ unsigned short tile[32][33];
  int bh = blockIdx.z;                 // b*NKV + kvh
  int b = bh >> 2, kvh = bh & 3;
  int t0 = blockIdx.x * 32, d0 = blockIdx.y * 32;
  int tx = threadIdx.x & 31, ty = threadIdx.x >> 5;
#pragma unroll
  for (int r = 0; r < 32; r += 8)
    tile[ty + r][tx] = qkv[(size_t)(b * T_ + t0 + ty + r) * NQKV_ + 2560 + kvh * HD_ + d0 + tx];
  __syncthreads();
#pragma unroll
  for (int r = 0; r < 32; r += 8)
    vt[(size_t)(bh * HD_ + d0 + ty + r) * T_ + t0 + tx] = tile[tx][ty + r];
}

// ---------------- 8-phase bf16 GEMM (T3+T4+T5), asm ds_read (R14, proven)
template <int BM, typename OUT, bool ROPE>
__global__ __launch_bounds__(512, 1) void gemm8p(const unsigned short* __restrict__ A,
                                                 const unsigned short* __restrict__ Bt,
                                                 OUT* __restrict__ Cm,
                                                 const float2* __restrict__ rt,
                                                 int M, int N, int K) {
  constexpr int MR = BM / 64;
  __shared__ __align__(16) unsigned short As[2][2][BM * 32];
  __shared__ __align__(16) unsigned short Bs[2][2][256 * 32];
  int tid = threadIdx.x, wid = tid >> 6, lane = tid & 63;
  int l15 = lane & 15, l4 = lane >> 4;
  int wr = wid >> 1, wc = wid & 1;
  size_t arow0 = (size_t)blockIdx.y * BM;
  size_t brow0 = (size_t)blockIdx.x * 256;
  int tmax = K / 64 - 1;

  f32x4 acc[MR][8];
#pragma unroll
  for (int m = 0; m < MR; ++m)
#pragma unroll
    for (int n = 0; n < 8; ++n) acc[m][n] = (f32x4){0.f, 0.f, 0.f, 0.f};

  auto stageA = [&](int slot, int kh, int tile) {
    int k0 = tile * 64 + kh * 32;
    constexpr int NLD = (BM * 32 * 2) / (512 * 16);
#pragma unroll
    for (int i = 0; i < NLD; ++i) {
      int c = i * 512 + wid * 64 + lane;
      int rg = c >> 2, cg = (c & 3) ^ (rg & 3);
      const unsigned short* g = A + (arow0 + rg) * K + k0 + cg * 8;
      GLOAD_LDS16(g, &As[slot][kh][c * 8]);
    }
  };
  auto stageB = [&](int slot, int kh, int tile) {
    int k0 = tile * 64 + kh * 32;
#pragma unroll
    for (int i = 0; i < 2; ++i) {
      int c = i * 512 + wid * 64 + lane;
      int rg = c >> 2, cg = (c & 3) ^ (rg & 3);
      const unsigned short* g = Bt + (brow0 + rg) * K + k0 + cg * 8;
      GLOAD_LDS16(g, &Bs[slot][kh][c * 8]);
    }
  };

  stageA(0, 0, 0); stageB(0, 0, 0); stageA(0, 1, 0); stageB(0, 1, 0);
  stageA(1, 0, 1); stageB(1, 0, 1); stageA(1, 1, 1);
  if constexpr (BM == 256) asm volatile("s_waitcnt vmcnt(6)" ::: "memory");
  else                     asm volatile("s_waitcnt vmcnt(4)" ::: "memory");
  __builtin_amdgcn_s_barrier();

  int NT2 = K / 128;
  for (int it = 0; it < NT2; ++it) {
    int t2 = it * 2;
#pragma unroll
    for (int tt = 0; tt < 2; ++tt) {
      bf16x8 af[MR];
#pragma unroll
      for (int kh = 0; kh < 2; ++kh) {
#pragma unroll
        for (int nh = 0; nh < 2; ++nh) {
          int p = tt * 4 + kh * 2 + nh + 1;
          if (nh == 0) {
#pragma unroll
            for (int m = 0; m < MR; ++m) {
              int r = wr * (MR * 16) + m * 16 + l15;
              af[m] = ldsread128(&As[tt][kh][r * 32 + ((l4 ^ (r & 3)) * 8)]);
            }
          }
          bf16x8 bf[4];
#pragma unroll
          for (int j = 0; j < 4; ++j) {
            int r = wc * 128 + (nh * 4 + j) * 16 + l15;
            bf[j] = ldsread128(&Bs[tt][kh][r * 32 + ((l4 ^ (r & 3)) * 8)]);
          }
          if (p == 1) stageB(1, 1, t2 + 1);
          if (p == 2) stageA(0, 0, t2 + 2 <= tmax ? t2 + 2 : tmax);
          if (p == 3) stageB(0, 0, t2 + 2 <= tmax ? t2 + 2 : tmax);
          if (p == 4) stageA(0, 1, t2 + 2 <= tmax ? t2 + 2 : tmax);
          if (p == 5) stageB(0, 1, t2 + 2 <= tmax ? t2 + 2 : tmax);
          if (p == 6) stageA(1, 0, t2 + 3 <= tmax ? t2 + 3 : tmax);
          if (p == 7) stageB(1, 0, t2 + 3 <= tmax ? t2 + 3 : tmax);
          if (p == 8) stageA(1, 1, t2 + 3 <= tmax ? t2 + 3 : tmax);

          __builtin_amdgcn_s_barrier();
          asm volatile("s_waitcnt lgkmcnt(0)" ::: "memory");
          __builtin_amdgcn_sched_barrier(0);
          __builtin_amdgcn_s_setprio(1);
#pragma unroll
          for (int m = 0; m < MR; ++m)
#pragma unroll
            for (int j = 0; j < 4; ++j)
              acc[m][nh * 4 + j] = __builtin_amdgcn_mfma_f32_16x16x32_bf16(
                  af[m], bf[j], acc[m][nh * 4 + j], 0, 0, 0);
          __builtin_amdgcn_s_setprio(0);
          if (p == 4 || p == 8) {
            if constexpr (BM == 256) asm volatile("s_waitcnt vmcnt(6)" ::: "memory");
            else                     asm volatile("s_waitcnt vmcnt(4)" ::: "memory");
          }
          __builtin_amdgcn_s_barrier();
        }
      }
    }
  }

  bool dorope = ROPE && (brow0 + wc * 128 < 2560);
#pragma unroll
  for (int m = 0; m < MR; ++m)
#pragma unroll
    for (int r = 0; r < 4; ++r) {
      size_t row = arow0 + wr * (MR * 16) + m * 16 + l4 * 4 + r;
      if (dorope) {
        int t = (int)(row & (T_ - 1));
#pragma unroll
        for (int n = 0; n < 4; ++n) {
          float2 cs = rt[t * 64 + n * 16 + l15];
          float a1 = acc[m][n][r], a2 = acc[m][n + 4][r];
          size_t col = brow0 + wc * 128 + n * 16 + l15;
          Cm[row * N + col]      = f2bf(a1 * cs.x - a2 * cs.y);
          Cm[row * N + col + 64] = f2bf(a2 * cs.x + a1 * cs.y);
        }
      } else {
#pragma unroll
        for (int n = 0; n < 8; ++n) {
          size_t col = brow0 + wc * 128 + n * 16 + l15;
          float v = acc[m][n][r];
          if constexpr (sizeof(OUT) == 4) Cm[row * N + col] = v;
          else                            Cm[row * N + col] = f2bf(v);
        }
      }
    }
}

// ---------------- flash attention (R8 inner loop, full-LPT KV-split):
// qi 15..8 split in two KV-halves (512 blocks), qi 7..0 unsplit (256), ids in
// descending-length order. Split half-0 stores unnormalized O in att (its own
// region) + m/l; half-1 in pO; combine merges in place. Inner loop identical
// to the proven R8/R15 structure.
__global__ __launch_bounds__(256, 2) void attn_kernel(const unsigned short* __restrict__ qkv,
                                                      const unsigned short* __restrict__ vt,
                                                      unsigned short* __restrict__ att,
                                                      unsigned short* __restrict__ pO,
                                                      float2* __restrict__ ml) {
  constexpr int KB = 64;
  __shared__ __align__(16) unsigned short Kl[2][KB * 128];
  __shared__ __align__(16) unsigned short Vl[2][128 * KB];
  int tid = threadIdx.x, w = tid >> 6, lane = tid & 63;
  int l31 = lane & 31, hi = lane >> 5;
  int h4 = hi * 4;

  // LPT decode (descending length): groups of (split qi / unsplit qi)
  int id = blockIdx.x;
  bool split;
  int qi, l;
  if      (id < 64)  { split = true;  qi = 15; l = id; }
  else if (id < 96)  { split = false; qi = 7;  l = id - 64; }
  else if (id < 160) { split = true;  qi = 14; l = id - 96; }
  else if (id < 224) { split = true;  qi = 13; l = id - 160; }
  else if (id < 256) { split = false; qi = 6;  l = id - 224; }
  else if (id < 320) { split = true;  qi = 12; l = id - 256; }
  else if (id < 384) { split = true;  qi = 11; l = id - 320; }
  else if (id < 416) { split = false; qi = 5;  l = id - 384; }
  else if (id < 480) { split = true;  qi = 10; l = id - 416; }
  else if (id < 544) { split = true;  qi = 9;  l = id - 480; }
  else if (id < 576) { split = false; qi = 4;  l = id - 544; }
  else if (id < 640) { split = true;  qi = 8;  l = id - 576; }
  else if (id < 672) { split = false; qi = 3;  l = id - 640; }
  else if (id < 704) { split = false; qi = 2;  l = id - 672; }
  else if (id < 736) { split = false; qi = 1;  l = id - 704; }
  else               { split = false; qi = 0;  l = id - 736; }
  int bh, kt0, kt1, pair = -1, half = 0;
  if (split) {
    bh = l >> 1; half = l & 1; pair = (15 - qi) * 32 + bh;
    int nt = 2 * qi + 2, h = qi + 1;
    kt0 = half ? h : 0; kt1 = half ? nt : h;
  } else {
    bh = l; kt0 = 0; kt1 = 2 * qi + 2;
  }
  int q0 = qi * 128;
  int b = bh >> 4, hd = bh & 15, kvh = hd >> 2;
  int qr0 = q0 + w * 32;
  int ql = qr0 + l31;

  bf16x8 qf[8];
  {
    const unsigned short* qb = qkv + (size_t)(b * T_ + ql) * NQKV_ + hd * HD_ + hi * 8;
    const float scale = 0.08838834764831845f * 1.4426950408889634f;
#pragma unroll
    for (int df = 0; df < 8; ++df) {
      bf16x8 t = *reinterpret_cast<const bf16x8*>(qb + df * 16);
#pragma unroll
      for (int j = 0; j < 8; ++j) t[j] = (__bf16)((float)t[j] * scale);
      qf[df] = t;
    }
  }

  f32x16 o[4];
#pragma unroll
  for (int dt = 0; dt < 4; ++dt)
#pragma unroll
    for (int r = 0; r < 16; ++r) o[dt][r] = 0.f;
  float mr = -1e30f, lr = 0.f;

  auto stage = [&](int buf, int kv0) {
#pragma unroll
    for (int i = 0; i < 4; ++i) {
      int c = (i * 4 + w) * 64 + lane;
      int g = c ^ ((c >> 4) & 7);
      const unsigned short* src =
          qkv + (size_t)(b * T_ + kv0 + (g >> 4)) * NQKV_ + C_ + kvh * HD_ + (g & 15) * 8;
      GLOAD_LDS16(src, &Kl[buf][(i * 4 + w) * 512]);
    }
#pragma unroll
    for (int i = 0; i < 4; ++i) {
      int c = (i * 4 + w) * 64 + lane;
      int g = c ^ ((c >> 3) & 7);
      const unsigned short* src =
          vt + (size_t)((b * NKV_ + kvh) * HD_ + (g >> 3)) * T_ + kv0 + (g & 7) * 8;
      GLOAD_LDS16(src, &Vl[buf][(i * 4 + w) * 512]);
    }
  };

  stage(0, kt0 * KB);
  __syncthreads();
  int cur = 0;
  for (int kt = kt0; kt < kt1; ++kt) {
    int kv0 = kt * KB;
    if (kt + 1 < kt1) stage(cur ^ 1, kv0 + KB);

    if (kv0 <= qr0 + 31) {
      f32x16 s[2];
#pragma unroll
      for (int r = 0; r < 16; ++r) { s[0][r] = 0.f; s[1][r] = 0.f; }
      const unsigned short* Kb = &Kl[cur][0];
      __builtin_amdgcn_s_setprio(1);
#pragma unroll
      for (int t2 = 0; t2 < 2; ++t2)
#pragma unroll
        for (int df = 0; df < 8; ++df) {
          bf16x8 kf = *reinterpret_cast<const bf16x8*>(
              Kb + (((t2 * 32 + l31) * 128 + df * 16 + hi * 8) ^ ((l31 & 7) << 3)));
          s[t2] = __builtin_amdgcn_mfma_f32_32x32x16_bf16(kf, qf[df], s[t2], 0, 0, 0);
        }
      __builtin_amdgcn_s_setprio(0);

      float rm = -1e30f;
      if ((kv0 + KB - 1) > qr0) {
#pragma unroll
        for (int t2 = 0; t2 < 2; ++t2)
#pragma unroll
          for (int r = 0; r < 16; ++r) {
            float sv = s[t2][r];
            int kcol = kv0 + t2 * 32 + (r & 3) + 8 * (r >> 2) + h4;
            if (kcol > ql) sv = -1e30f;
            s[t2][r] = sv;
            rm = fmaxf(rm, sv);
          }
      } else {
#pragma unroll
        for (int t2 = 0; t2 < 2; ++t2)
#pragma unroll
          for (int r = 0; r < 16; ++r) rm = fmaxf(rm, s[t2][r]);
      }
      rm = fmaxf(rm, __shfl_xor(rm, 32));

      if (!__all(rm <= mr + 11.0f)) {
        float mnew = fmaxf(mr, rm);
        float alpha = exp2f(mr - mnew);
        mr = mnew;
        lr *= alpha;
#pragma unroll
        for (int dt = 0; dt < 4; ++dt)
#pragma unroll
          for (int r = 0; r < 16; ++r) o[dt][r] *= alpha;
      }

      float ps = 0.f;
#pragma unroll
      for (int t2 = 0; t2 < 2; ++t2)
#pragma unroll
        for (int r = 0; r < 16; ++r) {
          float p = exp2f(s[t2][r] - mr);
          s[t2][r] = p;
          ps += p;
        }
      lr += ps;

      unsigned pk[2][8];
#pragma unroll
      for (int t2 = 0; t2 < 2; ++t2)
#pragma unroll
        for (int i = 0; i < 8; ++i) {
          union { unsigned u32; __bf16 hh[2]; } pr;
          pr.hh[0] = (__bf16)s[t2][2 * i];
          pr.hh[1] = (__bf16)s[t2][2 * i + 1];
          pk[t2][i] = pr.u32;
        }

      bf16x8 pb[4];
#pragma unroll
      for (int f = 0; f < 4; ++f) {
        int t2 = f >> 1, bq = (f & 1) * 4;
        union { bf16x8 v; unsigned d[4]; } fr;
#pragma unroll
        for (int p = 0; p < 2; ++p) {
          unsigned uu = pk[t2][bq + p];
          unsigned ww = pk[t2][bq + 2 + p];
          unsigned us = (unsigned)__shfl_xor((int)uu, 32);
          unsigned ws = (unsigned)__shfl_xor((int)ww, 32);
          fr.d[p]     = hi ? ws : uu;
          fr.d[2 + p] = hi ? ww : us;
        }
        pb[f] = fr.v;
      }

      const unsigned short* Vb = &Vl[cur][0];
      __builtin_amdgcn_s_setprio(1);
#pragma unroll
      for (int dt = 0; dt < 4; ++dt)
#pragma unroll
        for (int kf = 0; kf < 4; ++kf) {
          bf16x8 vf = *reinterpret_cast<const bf16x8*>(
              Vb + (((dt * 32 + l31) * KB + kf * 16 + hi * 8) ^ ((l31 & 7) << 3)));
          o[dt] = __builtin_amdgcn_mfma_f32_32x32x16_bf16(vf, pb[kf], o[dt], 0, 0, 0);
        }
      __builtin_amdgcn_s_setprio(0);
    }

    __syncthreads();
    cur ^= 1;
  }

  float ls = lr + __shfl_xor(lr, 32);
  if (pair < 0) {
    float inv = 1.f / ls;
    unsigned short* ob = att + (size_t)(b * T_ + ql) * C_ + hd * HD_;
#pragma unroll
    for (int dt = 0; dt < 4; ++dt)
#pragma unroll
      for (int r = 0; r < 16; ++r) {
        int d = dt * 32 + (r & 3) + 8 * (r >> 2) + h4;
        ob[d] = f2bf(o[dt][r] * inv);
      }
  } else if (half == 0) {
    // half-0 partial: unnormalized O stored in att's own region
    unsigned short* ob = att + (size_t)(b * T_ + ql) * C_ + hd * HD_;
#pragma unroll
    for (int dt = 0; dt < 4; ++dt)
#pragma unroll
      for (int r = 0; r < 16; ++r) {
        int d = dt * 32 + (r & 3) + 8 * (r >> 2) + h4;
        ob[d] = f2bf(o[dt][r]);
      }
    if (hi == 0) ml[(pair * 2) * 128 + w * 32 + l31] = make_float2(mr, ls);
  } else {
    // half-1 partial: pO slot
    int lrow = w * 32 + l31;
    unsigned short* po = pO + (size_t)pair * 16384 + lrow * 128;
#pragma unroll
    for (int dt = 0; dt < 4; ++dt)
#pragma unroll
      for (int r = 0; r < 16; ++r) {
        int d = dt * 32 + (r & 3) + 8 * (r >> 2) + h4;
        po[d] = f2bf(o[dt][r]);
      }
    if (hi == 0) ml[(pair * 2 + 1) * 128 + lrow] = make_float2(mr, ls);
  }
}

// ---------------- merge KV-split halves in place:
// att (half0, unnormalized) + pO (half1) -> att = (w0*O0 + w1*O1)/(w0*l0+w1*l1)
__global__ void combine_kernel(const unsigned short* __restrict__ pO,
                               const float2* __restrict__ ml,
                               unsigned short* __restrict__ att) {
  int pair = blockIdx.x;               // 0..255
  int qi = 15 - (pair >> 5), bh = pair & 31;
  int b = bh >> 4, hd = bh & 15;
  int q0 = qi * 128;
  int tid = threadIdx.x;               // 256: 2 threads per row, 64 d each
  int row = tid >> 1, dh = (tid & 1) * 64;
  float2 ml0 = ml[(pair * 2) * 128 + row], ml1 = ml[(pair * 2 + 1) * 128 + row];
  float m = fmaxf(ml0.x, ml1.x);
  float w0 = exp2f(ml0.x - m), w1 = exp2f(ml1.x - m);
  float inv = 1.f / (w0 * ml0.y + w1 * ml1.y);
  unsigned short* ob = att + (size_t)(b * T_ + q0 + row) * C_ + hd * HD_ + dh;
  const unsigned short* p1 = pO + (size_t)pair * 16384 + row * 128 + dh;
#pragma unroll
  for (int j = 0; j < 64; j += 4) {
    ushort4 a = *reinterpret_cast<const ushort4*>(ob + j);
    ushort4 c = *reinterpret_cast<const ushort4*>(p1 + j);
    ushort4 r;
    r.x = f2bf((w0 * bf2f(a.x) + w1 * bf2f(c.x)) * inv);
    r.y = f2bf((w0 * bf2f(a.y) + w1 * bf2f(c.y)) * inv);
    r.z = f2bf((w0 * bf2f(a.z) + w1 * bf2f(c.z)) * inv);
    r.w = f2bf((w0 * bf2f(a.w) + w1 * bf2f(c.w)) * inv);
    *reinterpret_cast<ushort4*>(ob + j) = r;
  }
}

extern "C" void kernel_launch(void* const* d_in, const int* in_sizes, int n_in,
                              void* d_out, int out_size, void* d_ws, size_t ws_size,
                              hipStream_t stream) {
  const float* x  = (const float*)d_in[0];
  const float* Wq = (const float*)d_in[1];
  const float* Wk = (const float*)d_in[2];
  const float* Wv = (const float*)d_in[3];
  const float* Wp = (const float*)d_in[4];
  float* out = (float*)d_out;
  char* ws = (char*)d_ws;

  // workspace layout (bytes); total 68,157,440
  unsigned short* xb  = (unsigned short*)(ws);              // 16MB  x bf16 (att aliases)
  unsigned short* wt  = (unsigned short*)(ws + 16777216);   // 20MB  Wq^T|Wk^T|Wv^T|Wp^T
  unsigned short* qkv = (unsigned short*)(ws + 37748736);   // 24MB  q(rope)|k(rope)|v
  float2*         rt  = (float2*)(ws + 62914560);           // 1MB   cos/sin (dead after GEMM1)
  unsigned short* vt  = (unsigned short*)(ws + 63963136);   // 4MB   V d-major [bh*HD+d][t]
  unsigned short* att = xb;                                 // alias: xb dead after GEMM1
  unsigned short* pO  = wt;                                 // alias: Wq/k/v^T dead (8MB used of 12MB)
  float2*         ml  = rt;                                 // alias: rt dead after GEMM1 (512KB)

  prep_kernel<<<dim3(18944), 256, 0, stream>>>(x, Wq, Wk, Wv, Wp, xb, wt, rt);

  gemm8p<256, unsigned short, true><<<dim3(NQKV_ / 256, M_ / 256), 512, 0, stream>>>(
      xb, wt, qkv, rt, M_, NQKV_, C_);
  transpose_v_kernel<<<dim3(T_ / 32, HD_ / 32, B_ * NKV_), 256, 0, stream>>>(qkv, vt);
  attn_kernel<<<dim3(768), 256, 0, stream>>>(qkv, vt, att, pO, ml);
  combine_kernel<<<dim3(256), 256, 0, stream>>>(pO, ml, att);
  gemm8p<128, float, false><<<dim3(C_ / 256, M_ / 128), 512, 0, stream>>>(
      att, wt + (size_t)3072 * 2048, out, nullptr, M_, C_, C_);
}

// Round 19
// 213.464 us; speedup vs baseline: 1.3235x; 1.0161x over previous
//
#include <hip/hip_runtime.h>

#define B_ 2
#define T_ 2048
#define C_ 2048
#define NH_ 16
#define NKV_ 4
#define HD_ 128
#define M_ 4096          // B*T
#define NQKV_ 3072

typedef __bf16 bf16x8 __attribute__((ext_vector_type(8)));
typedef float f32x4 __attribute__((ext_vector_type(4)));
typedef float f32x16 __attribute__((ext_vector_type(16)));

__device__ __forceinline__ unsigned short f2bf(float f) {
  union { float f; unsigned u; } c{f};
  unsigned u = c.u + 0x7FFFu + ((c.u >> 16) & 1u);
  return (unsigned short)(u >> 16);
}
__device__ __forceinline__ float bf2f(unsigned short h) {
  union { unsigned u; float f; } c{(unsigned)h << 16};
  return c.f;
}

#define GLOAD_LDS16(g, l)                                        \
  __builtin_amdgcn_global_load_lds(                              \
      (const __attribute__((address_space(1))) void*)(g),        \
      (__attribute__((address_space(3))) void*)(l), 16, 0, 0)

// asm ds_read_b128 (rule #18: fence with lgkmcnt(0)+sched_barrier(0) before use)
__device__ __forceinline__ bf16x8 ldsread128(const unsigned short* p) {
  uint4 d;
  asm volatile("ds_read_b128 %0, %1"
               : "=v"(d)
               : "v"((const __attribute__((address_space(3))) void*)p));
  union { uint4 u; bf16x8 v; } c;
  c.u = d;
  return c.v;
}

// ---------------- fused prep: weight transposes + x->bf16 + rope table
__global__ void prep_kernel(const float* __restrict__ x, const float* __restrict__ Wq,
                            const float* __restrict__ Wk, const float* __restrict__ Wv,
                            const float* __restrict__ Wp, unsigned short* __restrict__ xb,
                            unsigned short* __restrict__ wt, float2* __restrict__ rt) {
  int id = blockIdx.x;
  if (id < 10240) {  // weight transpose-convert
    __shared__ float tile[32][33];
    const float* W;
    unsigned short* Wt;
    int N, bx, by;
    if (id < 4096)      { W = Wq; Wt = wt;                       N = 2048; int u = id;        bx = u & 63; by = u >> 6; }
    else if (id < 5120) { W = Wk; Wt = wt + (size_t)2048 * 2048; N = 512;  int u = id - 4096; bx = u & 15; by = u >> 4; }
    else if (id < 6144) { W = Wv; Wt = wt + (size_t)2560 * 2048; N = 512;  int u = id - 5120; bx = u & 15; by = u >> 4; }
    else                { W = Wp; Wt = wt + (size_t)3072 * 2048; N = 2048; int u = id - 6144; bx = u & 63; by = u >> 6; }
    const int K = 2048;
    bx *= 32; by *= 32;
    int tx = threadIdx.x & 31, ty = threadIdx.x >> 5;
#pragma unroll
    for (int r = 0; r < 32; r += 8)
      tile[ty + r][tx] = W[(size_t)(by + ty + r) * N + bx + tx];
    __syncthreads();
#pragma unroll
    for (int r = 0; r < 32; r += 8)
      Wt[(size_t)(bx + ty + r) * K + by + tx] = f2bf(tile[tx][ty + r]);
  } else if (id < 18432) {  // x f32 -> bf16, float4 chunks
    int i = (id - 10240) * 256 + threadIdx.x;
    float4 v = reinterpret_cast<const float4*>(x)[i];
    union { ushort4 u; unsigned short s[4]; } o;
    o.s[0] = f2bf(v.x); o.s[1] = f2bf(v.y); o.s[2] = f2bf(v.z); o.s[3] = f2bf(v.w);
    reinterpret_cast<ushort4*>(xb)[i] = o.u;
  } else {  // rope table
    int g = (id - 18432) * 256 + threadIdx.x;
    int t = g >> 6, i = g & 63;
    float inv = powf(10000.f, -(float)(2 * i) / 128.f);
    float s, c;
    sincosf((float)t * inv, &s, &c);
    rt[t * 64 + i] = make_float2(c, s);
  }
}

// ---------------- V slice of qkv -> vt[(b*NKV+kvh)*HD + d][t]  (bf16 transpose)
__global__ void transpose_v_kernel(const unsigned short* __restrict__ qkv,
                                   unsigned short* __restrict__ vt) {
  __shared__ unsigned short tile[32][33];
  int bh = blockIdx.z;                 // b*NKV + kvh
  int b = bh >> 2, kvh = bh & 3;
  int t0 = blockIdx.x * 32, d0 = blockIdx.y * 32;
  int tx = threadIdx.x & 31, ty = threadIdx.x >> 5;
#pragma unroll
  for (int r = 0; r < 32; r += 8)
    tile[ty + r][tx] = qkv[(size_t)(b * T_ + t0 + ty + r) * NQKV_ + 2560 + kvh * HD_ + d0 + tx];
  __syncthreads();
#pragma unroll
  for (int r = 0; r < 32; r += 8)
    vt[(size_t)(bh * HD_ + d0 + ty + r) * T_ + t0 + tx] = tile[tx][ty + r];
}

// ---------------- 8-phase bf16 GEMM (T3+T4+T5), asm ds_read (R14, proven)
template <int BM, typename OUT, bool ROPE>
__global__ __launch_bounds__(512, 1) void gemm8p(const unsigned short* __restrict__ A,
                                                 const unsigned short* __restrict__ Bt,
                                                 OUT* __restrict__ Cm,
                                                 const float2* __restrict__ rt,
                                                 int M, int N, int K) {
  constexpr int MR = BM / 64;
  __shared__ __align__(16) unsigned short As[2][2][BM * 32];
  __shared__ __align__(16) unsigned short Bs[2][2][256 * 32];
  int tid = threadIdx.x, wid = tid >> 6, lane = tid & 63;
  int l15 = lane & 15, l4 = lane >> 4;
  int wr = wid >> 1, wc = wid & 1;
  size_t arow0 = (size_t)blockIdx.y * BM;
  size_t brow0 = (size_t)blockIdx.x * 256;
  int tmax = K / 64 - 1;

  f32x4 acc[MR][8];
#pragma unroll
  for (int m = 0; m < MR; ++m)
#pragma unroll
    for (int n = 0; n < 8; ++n) acc[m][n] = (f32x4){0.f, 0.f, 0.f, 0.f};

  auto stageA = [&](int slot, int kh, int tile) {
    int k0 = tile * 64 + kh * 32;
    constexpr int NLD = (BM * 32 * 2) / (512 * 16);
#pragma unroll
    for (int i = 0; i < NLD; ++i) {
      int c = i * 512 + wid * 64 + lane;
      int rg = c >> 2, cg = (c & 3) ^ (rg & 3);
      const unsigned short* g = A + (arow0 + rg) * K + k0 + cg * 8;
      GLOAD_LDS16(g, &As[slot][kh][c * 8]);
    }
  };
  auto stageB = [&](int slot, int kh, int tile) {
    int k0 = tile * 64 + kh * 32;
#pragma unroll
    for (int i = 0; i < 2; ++i) {
      int c = i * 512 + wid * 64 + lane;
      int rg = c >> 2, cg = (c & 3) ^ (rg & 3);
      const unsigned short* g = Bt + (brow0 + rg) * K + k0 + cg * 8;
      GLOAD_LDS16(g, &Bs[slot][kh][c * 8]);
    }
  };

  stageA(0, 0, 0); stageB(0, 0, 0); stageA(0, 1, 0); stageB(0, 1, 0);
  stageA(1, 0, 1); stageB(1, 0, 1); stageA(1, 1, 1);
  if constexpr (BM == 256) asm volatile("s_waitcnt vmcnt(6)" ::: "memory");
  else                     asm volatile("s_waitcnt vmcnt(4)" ::: "memory");
  __builtin_amdgcn_s_barrier();

  int NT2 = K / 128;
  for (int it = 0; it < NT2; ++it) {
    int t2 = it * 2;
#pragma unroll
    for (int tt = 0; tt < 2; ++tt) {
      bf16x8 af[MR];
#pragma unroll
      for (int kh = 0; kh < 2; ++kh) {
#pragma unroll
        for (int nh = 0; nh < 2; ++nh) {
          int p = tt * 4 + kh * 2 + nh + 1;
          if (nh == 0) {
#pragma unroll
            for (int m = 0; m < MR; ++m) {
              int r = wr * (MR * 16) + m * 16 + l15;
              af[m] = ldsread128(&As[tt][kh][r * 32 + ((l4 ^ (r & 3)) * 8)]);
            }
          }
          bf16x8 bf[4];
#pragma unroll
          for (int j = 0; j < 4; ++j) {
            int r = wc * 128 + (nh * 4 + j) * 16 + l15;
            bf[j] = ldsread128(&Bs[tt][kh][r * 32 + ((l4 ^ (r & 3)) * 8)]);
          }
          if (p == 1) stageB(1, 1, t2 + 1);
          if (p == 2) stageA(0, 0, t2 + 2 <= tmax ? t2 + 2 : tmax);
          if (p == 3) stageB(0, 0, t2 + 2 <= tmax ? t2 + 2 : tmax);
          if (p == 4) stageA(0, 1, t2 + 2 <= tmax ? t2 + 2 : tmax);
          if (p == 5) stageB(0, 1, t2 + 2 <= tmax ? t2 + 2 : tmax);
          if (p == 6) stageA(1, 0, t2 + 3 <= tmax ? t2 + 3 : tmax);
          if (p == 7) stageB(1, 0, t2 + 3 <= tmax ? t2 + 3 : tmax);
          if (p == 8) stageA(1, 1, t2 + 3 <= tmax ? t2 + 3 : tmax);

          __builtin_amdgcn_s_barrier();
          asm volatile("s_waitcnt lgkmcnt(0)" ::: "memory");
          __builtin_amdgcn_sched_barrier(0);
          __builtin_amdgcn_s_setprio(1);
#pragma unroll
          for (int m = 0; m < MR; ++m)
#pragma unroll
            for (int j = 0; j < 4; ++j)
              acc[m][nh * 4 + j] = __builtin_amdgcn_mfma_f32_16x16x32_bf16(
                  af[m], bf[j], acc[m][nh * 4 + j], 0, 0, 0);
          __builtin_amdgcn_s_setprio(0);
          if (p == 4 || p == 8) {
            if constexpr (BM == 256) asm volatile("s_waitcnt vmcnt(6)" ::: "memory");
            else                     asm volatile("s_waitcnt vmcnt(4)" ::: "memory");
          }
          __builtin_amdgcn_s_barrier();
        }
      }
    }
  }

  bool dorope = ROPE && (brow0 + wc * 128 < 2560);
#pragma unroll
  for (int m = 0; m < MR; ++m)
#pragma unroll
    for (int r = 0; r < 4; ++r) {
      size_t row = arow0 + wr * (MR * 16) + m * 16 + l4 * 4 + r;
      if (dorope) {
        int t = (int)(row & (T_ - 1));
#pragma unroll
        for (int n = 0; n < 4; ++n) {
          float2 cs = rt[t * 64 + n * 16 + l15];
          float a1 = acc[m][n][r], a2 = acc[m][n + 4][r];
          size_t col = brow0 + wc * 128 + n * 16 + l15;
          Cm[row * N + col]      = f2bf(a1 * cs.x - a2 * cs.y);
          Cm[row * N + col + 64] = f2bf(a2 * cs.x + a1 * cs.y);
        }
      } else {
#pragma unroll
        for (int n = 0; n < 8; ++n) {
          size_t col = brow0 + wc * 128 + n * 16 + l15;
          float v = acc[m][n][r];
          if constexpr (sizeof(OUT) == 4) Cm[row * N + col] = v;
          else                            Cm[row * N + col] = f2bf(v);
        }
      }
    }
}

// ---------------- flash attention (R8 inner loop, KV-split scheduling — R15):
// 704 blocks, LPT order: qi 9,8 unsplit (longest) -> qi 15..10 split in two
// KV-halves (partial m/l/O output) -> qi 7..0 unsplit. Combine merges halves.
__global__ __launch_bounds__(256, 2) void attn_kernel(const unsigned short* __restrict__ qkv,
                                                      const unsigned short* __restrict__ vt,
                                                      unsigned short* __restrict__ att,
                                                      unsigned short* __restrict__ pO,
                                                      float2* __restrict__ ml) {
  constexpr int KB = 64;
  __shared__ __align__(16) unsigned short Kl[2][KB * 128];
  __shared__ __align__(16) unsigned short Vl[2][128 * KB];
  int tid = threadIdx.x, w = tid >> 6, lane = tid & 63;
  int l31 = lane & 31, hi = lane >> 5;
  int h4 = hi * 4;

  // LPT decode
  int id = blockIdx.x;
  int qi, bh, kt0, kt1, slot = -1;
  if (id < 64) {                       // unsplit qi 9,8 (longest items first)
    qi = 9 - (id >> 5); bh = id & 31; kt0 = 0; kt1 = 2 * qi + 2;
  } else if (id < 448) {               // split qi 15..10, two KV halves
    int s = id - 64;
    int pairidx = s >> 1, hihalf = s & 1;
    qi = 15 - (pairidx >> 5); bh = pairidx & 31;
    int nt = 2 * qi + 2, h = nt >> 1;
    kt0 = hihalf ? h : 0; kt1 = hihalf ? nt : h;
    slot = s;
  } else {                             // unsplit qi 7..0
    int u = id - 448;
    qi = 7 - (u >> 5); bh = u & 31; kt0 = 0; kt1 = 2 * qi + 2;
  }
  int q0 = qi * 128;
  int b = bh >> 4, hd = bh & 15, kvh = hd >> 2;
  int qr0 = q0 + w * 32;
  int ql = qr0 + l31;

  bf16x8 qf[8];
  {
    const unsigned short* qb = qkv + (size_t)(b * T_ + ql) * NQKV_ + hd * HD_ + hi * 8;
    const float scale = 0.08838834764831845f * 1.4426950408889634f;
#pragma unroll
    for (int df = 0; df < 8; ++df) {
      bf16x8 t = *reinterpret_cast<const bf16x8*>(qb + df * 16);
#pragma unroll
      for (int j = 0; j < 8; ++j) t[j] = (__bf16)((float)t[j] * scale);
      qf[df] = t;
    }
  }

  f32x16 o[4];
#pragma unroll
  for (int dt = 0; dt < 4; ++dt)
#pragma unroll
    for (int r = 0; r < 16; ++r) o[dt][r] = 0.f;
  float mr = -1e30f, lr = 0.f;

  auto stage = [&](int buf, int kv0) {
#pragma unroll
    for (int i = 0; i < 4; ++i) {
      int c = (i * 4 + w) * 64 + lane;
      int g = c ^ ((c >> 4) & 7);
      const unsigned short* src =
          qkv + (size_t)(b * T_ + kv0 + (g >> 4)) * NQKV_ + C_ + kvh * HD_ + (g & 15) * 8;
      GLOAD_LDS16(src, &Kl[buf][(i * 4 + w) * 512]);
    }
#pragma unroll
    for (int i = 0; i < 4; ++i) {
      int c = (i * 4 + w) * 64 + lane;
      int g = c ^ ((c >> 3) & 7);
      const unsigned short* src =
          vt + (size_t)((b * NKV_ + kvh) * HD_ + (g >> 3)) * T_ + kv0 + (g & 7) * 8;
      GLOAD_LDS16(src, &Vl[buf][(i * 4 + w) * 512]);
    }
  };

  stage(0, kt0 * KB);
  __syncthreads();
  int cur = 0;
  for (int kt = kt0; kt < kt1; ++kt) {
    int kv0 = kt * KB;
    if (kt + 1 < kt1) stage(cur ^ 1, kv0 + KB);

    if (kv0 <= qr0 + 31) {
      f32x16 s[2];
#pragma unroll
      for (int r = 0; r < 16; ++r) { s[0][r] = 0.f; s[1][r] = 0.f; }
      const unsigned short* Kb = &Kl[cur][0];
      __builtin_amdgcn_s_setprio(1);
#pragma unroll
      for (int t2 = 0; t2 < 2; ++t2)
#pragma unroll
        for (int df = 0; df < 8; ++df) {
          bf16x8 kf = *reinterpret_cast<const bf16x8*>(
              Kb + (((t2 * 32 + l31) * 128 + df * 16 + hi * 8) ^ ((l31 & 7) << 3)));
          s[t2] = __builtin_amdgcn_mfma_f32_32x32x16_bf16(kf, qf[df], s[t2], 0, 0, 0);
        }
      __builtin_amdgcn_s_setprio(0);

      float rm = -1e30f;
      if ((kv0 + KB - 1) > qr0) {
#pragma unroll
        for (int t2 = 0; t2 < 2; ++t2)
#pragma unroll
          for (int r = 0; r < 16; ++r) {
            float sv = s[t2][r];
            int kcol = kv0 + t2 * 32 + (r & 3) + 8 * (r >> 2) + h4;
            if (kcol > ql) sv = -1e30f;
            s[t2][r] = sv;
            rm = fmaxf(rm, sv);
          }
      } else {
#pragma unroll
        for (int t2 = 0; t2 < 2; ++t2)
#pragma unroll
          for (int r = 0; r < 16; ++r) rm = fmaxf(rm, s[t2][r]);
      }
      rm = fmaxf(rm, __shfl_xor(rm, 32));

      if (!__all(rm <= mr + 11.0f)) {
        float mnew = fmaxf(mr, rm);
        float alpha = exp2f(mr - mnew);
        mr = mnew;
        lr *= alpha;
#pragma unroll
        for (int dt = 0; dt < 4; ++dt)
#pragma unroll
          for (int r = 0; r < 16; ++r) o[dt][r] *= alpha;
      }

      float ps = 0.f;
#pragma unroll
      for (int t2 = 0; t2 < 2; ++t2)
#pragma unroll
        for (int r = 0; r < 16; ++r) {
          float p = exp2f(s[t2][r] - mr);
          s[t2][r] = p;
          ps += p;
        }
      lr += ps;

      unsigned pk[2][8];
#pragma unroll
      for (int t2 = 0; t2 < 2; ++t2)
#pragma unroll
        for (int i = 0; i < 8; ++i) {
          union { unsigned u32; __bf16 hh[2]; } pr;
          pr.hh[0] = (__bf16)s[t2][2 * i];
          pr.hh[1] = (__bf16)s[t2][2 * i + 1];
          pk[t2][i] = pr.u32;
        }

      bf16x8 pb[4];
#pragma unroll
      for (int f = 0; f < 4; ++f) {
        int t2 = f >> 1, bq = (f & 1) * 4;
        union { bf16x8 v; unsigned d[4]; } fr;
#pragma unroll
        for (int p = 0; p < 2; ++p) {
          unsigned uu = pk[t2][bq + p];
          unsigned ww = pk[t2][bq + 2 + p];
          unsigned us = (unsigned)__shfl_xor((int)uu, 32);
          unsigned ws = (unsigned)__shfl_xor((int)ww, 32);
          fr.d[p]     = hi ? ws : uu;
          fr.d[2 + p] = hi ? ww : us;
        }
        pb[f] = fr.v;
      }

      const unsigned short* Vb = &Vl[cur][0];
      __builtin_amdgcn_s_setprio(1);
#pragma unroll
      for (int dt = 0; dt < 4; ++dt)
#pragma unroll
        for (int kf = 0; kf < 4; ++kf) {
          bf16x8 vf = *reinterpret_cast<const bf16x8*>(
              Vb + (((dt * 32 + l31) * KB + kf * 16 + hi * 8) ^ ((l31 & 7) << 3)));
          o[dt] = __builtin_amdgcn_mfma_f32_32x32x16_bf16(vf, pb[kf], o[dt], 0, 0, 0);
        }
      __builtin_amdgcn_s_setprio(0);
    }

    __syncthreads();
    cur ^= 1;
  }

  float ls = lr + __shfl_xor(lr, 32);
  if (slot < 0) {
    float inv = 1.f / ls;
    unsigned short* ob = att + (size_t)(b * T_ + ql) * C_ + hd * HD_;
#pragma unroll
    for (int dt = 0; dt < 4; ++dt)
#pragma unroll
      for (int r = 0; r < 16; ++r) {
        int d = dt * 32 + (r & 3) + 8 * (r >> 2) + h4;
        ob[d] = f2bf(o[dt][r] * inv);
      }
  } else {
    int lrow = w * 32 + l31;
    unsigned short* po = pO + (size_t)slot * 16384 + lrow * 128;
#pragma unroll
    for (int dt = 0; dt < 4; ++dt)
#pragma unroll
      for (int r = 0; r < 16; ++r) {
        int d = dt * 32 + (r & 3) + 8 * (r >> 2) + h4;
        po[d] = f2bf(o[dt][r]);
      }
    if (hi == 0) ml[slot * 128 + lrow] = make_float2(mr, ls);
  }
}

// ---------------- merge KV-split halves: O = (w0*O0 + w1*O1) / (w0*l0 + w1*l1)
__global__ void combine_kernel(const unsigned short* __restrict__ pO,
                               const float2* __restrict__ ml,
                               unsigned short* __restrict__ att) {
  int pairidx = blockIdx.x;            // 0..191
  int qi = 15 - (pairidx >> 5), bh = pairidx & 31;
  int b = bh >> 4, hd = bh & 15;
  int q0 = qi * 128;
  int s0 = pairidx * 2, s1 = s0 + 1;
  int tid = threadIdx.x;               // 256: 2 threads per row, 64 d each
  int row = tid >> 1, dh = (tid & 1) * 64;
  float2 ml0 = ml[s0 * 128 + row], ml1 = ml[s1 * 128 + row];
  float m = fmaxf(ml0.x, ml1.x);
  float w0 = exp2f(ml0.x - m), w1 = exp2f(ml1.x - m);
  float inv = 1.f / (w0 * ml0.y + w1 * ml1.y);
  const unsigned short* p0 = pO + (size_t)s0 * 16384 + row * 128 + dh;
  const unsigned short* p1 = pO + (size_t)s1 * 16384 + row * 128 + dh;
  unsigned short* ob = att + (size_t)(b * T_ + q0 + row) * C_ + hd * HD_ + dh;
#pragma unroll
  for (int j = 0; j < 64; j += 4) {
    ushort4 a = *reinterpret_cast<const ushort4*>(p0 + j);
    ushort4 c = *reinterpret_cast<const ushort4*>(p1 + j);
    ushort4 r;
    r.x = f2bf((w0 * bf2f(a.x) + w1 * bf2f(c.x)) * inv);
    r.y = f2bf((w0 * bf2f(a.y) + w1 * bf2f(c.y)) * inv);
    r.z = f2bf((w0 * bf2f(a.z) + w1 * bf2f(c.z)) * inv);
    r.w = f2bf((w0 * bf2f(a.w) + w1 * bf2f(c.w)) * inv);
    *reinterpret_cast<ushort4*>(ob + j) = r;
  }
}

extern "C" void kernel_launch(void* const* d_in, const int* in_sizes, int n_in,
                              void* d_out, int out_size, void* d_ws, size_t ws_size,
                              hipStream_t stream) {
  const float* x  = (const float*)d_in[0];
  const float* Wq = (const float*)d_in[1];
  const float* Wk = (const float*)d_in[2];
  const float* Wv = (const float*)d_in[3];
  const float* Wp = (const float*)d_in[4];
  float* out = (float*)d_out;
  char* ws = (char*)d_ws;

  // workspace layout (bytes); total 68,157,440
  unsigned short* xb  = (unsigned short*)(ws);              // 16MB  x bf16 (att aliases)
  unsigned short* wt  = (unsigned short*)(ws + 16777216);   // 20MB  Wq^T|Wk^T|Wv^T|Wp^T
  unsigned short* qkv = (unsigned short*)(ws + 37748736);   // 24MB  q(rope)|k(rope)|v
  float2*         rt  = (float2*)(ws + 62914560);           // 1MB   cos/sin (dead after GEMM1)
  unsigned short* vt  = (unsigned short*)(ws + 63963136);   // 4MB   V d-major [bh*HD+d][t]
  unsigned short* att = xb;                                 // alias: xb dead after GEMM1
  unsigned short* pO  = wt;                                 // alias: Wq/k/v^T dead after GEMM1
  float2*         ml  = rt;                                 // alias: rt dead after GEMM1

  prep_kernel<<<dim3(18944), 256, 0, stream>>>(x, Wq, Wk, Wv, Wp, xb, wt, rt);

  gemm8p<256, unsigned short, true><<<dim3(NQKV_ / 256, M_ / 256), 512, 0, stream>>>(
      xb, wt, qkv, rt, M_, NQKV_, C_);
  transpose_v_kernel<<<dim3(T_ / 32, HD_ / 32, B_ * NKV_), 256, 0, stream>>>(qkv, vt);
  attn_kernel<<<dim3(704), 256, 0, stream>>>(qkv, vt, att, pO, ml);
  combine_kernel<<<dim3(192), 256, 0, stream>>>(pO, ml, att);
  gemm8p<128, float, false><<<dim3(C_ / 256, M_ / 128), 512, 0, stream>>>(
      att, wt + (size_t)3072 * 2048, out, nullptr, M_, C_, C_);
}

// Round 20
// 212.252 us; speedup vs baseline: 1.3310x; 1.0057x over previous
//
#include <hip/hip_runtime.h>

#define B_ 2
#define T_ 2048
#define C_ 2048
#define NH_ 16
#define NKV_ 4
#define HD_ 128
#define M_ 4096          // B*T
#define NQKV_ 3072

typedef __bf16 bf16x8 __attribute__((ext_vector_type(8)));
typedef float f32x4 __attribute__((ext_vector_type(4)));
typedef float f32x16 __attribute__((ext_vector_type(16)));

__device__ __forceinline__ unsigned short f2bf(float f) {
  union { float f; unsigned u; } c{f};
  unsigned u = c.u + 0x7FFFu + ((c.u >> 16) & 1u);
  return (unsigned short)(u >> 16);
}
__device__ __forceinline__ float bf2f(unsigned short h) {
  union { unsigned u; float f; } c{(unsigned)h << 16};
  return c.f;
}

#define GLOAD_LDS16(g, l)                                        \
  __builtin_amdgcn_global_load_lds(                              \
      (const __attribute__((address_space(1))) void*)(g),        \
      (__attribute__((address_space(3))) void*)(l), 16, 0, 0)

// asm ds_read_b128 (rule #18: fence with lgkmcnt(0)+sched_barrier(0) before use)
__device__ __forceinline__ bf16x8 ldsread128(const unsigned short* p) {
  uint4 d;
  asm volatile("ds_read_b128 %0, %1"
               : "=v"(d)
               : "v"((const __attribute__((address_space(3))) void*)p));
  union { uint4 u; bf16x8 v; } c;
  c.u = d;
  return c.v;
}

// ---------------- fused prep: weight transposes + x->bf16 + rope table
__global__ void prep_kernel(const float* __restrict__ x, const float* __restrict__ Wq,
                            const float* __restrict__ Wk, const float* __restrict__ Wv,
                            const float* __restrict__ Wp, unsigned short* __restrict__ xb,
                            unsigned short* __restrict__ wt, float2* __restrict__ rt) {
  int id = blockIdx.x;
  if (id < 10240) {  // weight transpose-convert
    __shared__ float tile[32][33];
    const float* W;
    unsigned short* Wt;
    int N, bx, by;
    if (id < 4096)      { W = Wq; Wt = wt;                       N = 2048; int u = id;        bx = u & 63; by = u >> 6; }
    else if (id < 5120) { W = Wk; Wt = wt + (size_t)2048 * 2048; N = 512;  int u = id - 4096; bx = u & 15; by = u >> 4; }
    else if (id < 6144) { W = Wv; Wt = wt + (size_t)2560 * 2048; N = 512;  int u = id - 5120; bx = u & 15; by = u >> 4; }
    else                { W = Wp; Wt = wt + (size_t)3072 * 2048; N = 2048; int u = id - 6144; bx = u & 63; by = u >> 6; }
    const int K = 2048;
    bx *= 32; by *= 32;
    int tx = threadIdx.x & 31, ty = threadIdx.x >> 5;
#pragma unroll
    for (int r = 0; r < 32; r += 8)
      tile[ty + r][tx] = W[(size_t)(by + ty + r) * N + bx + tx];
    __syncthreads();
#pragma unroll
    for (int r = 0; r < 32; r += 8)
      Wt[(size_t)(bx + ty + r) * K + by + tx] = f2bf(tile[tx][ty + r]);
  } else if (id < 18432) {  // x f32 -> bf16, float4 chunks
    int i = (id - 10240) * 256 + threadIdx.x;
    float4 v = reinterpret_cast<const float4*>(x)[i];
    union { ushort4 u; unsigned short s[4]; } o;
    o.s[0] = f2bf(v.x); o.s[1] = f2bf(v.y); o.s[2] = f2bf(v.z); o.s[3] = f2bf(v.w);
    reinterpret_cast<ushort4*>(xb)[i] = o.u;
  } else {  // rope table
    int g = (id - 18432) * 256 + threadIdx.x;
    int t = g >> 6, i = g & 63;
    float inv = powf(10000.f, -(float)(2 * i) / 128.f);
    float s, c;
    sincosf((float)t * inv, &s, &c);
    rt[t * 64 + i] = make_float2(c, s);
  }
}

// ---------------- 8-phase bf16 GEMM (T3+T4+T5), asm ds_read (R14, proven).
// QKV=true epilogue: q,k -> rope -> qkv; V head-blocks -> vt d-major directly
// (wave's 128-col strip == one KV head; 4 r-values = 4 consecutive t -> ushort4).
template <int BM, typename OUT, bool QKV>
__global__ __launch_bounds__(512, 1) void gemm8p(const unsigned short* __restrict__ A,
                                                 const unsigned short* __restrict__ Bt,
                                                 OUT* __restrict__ Cm,
                                                 unsigned short* __restrict__ vtp,
                                                 const float2* __restrict__ rt,
                                                 int M, int N, int K) {
  constexpr int MR = BM / 64;
  __shared__ __align__(16) unsigned short As[2][2][BM * 32];
  __shared__ __align__(16) unsigned short Bs[2][2][256 * 32];
  int tid = threadIdx.x, wid = tid >> 6, lane = tid & 63;
  int l15 = lane & 15, l4 = lane >> 4;
  int wr = wid >> 1, wc = wid & 1;
  size_t arow0 = (size_t)blockIdx.y * BM;
  size_t brow0 = (size_t)blockIdx.x * 256;
  int tmax = K / 64 - 1;

  f32x4 acc[MR][8];
#pragma unroll
  for (int m = 0; m < MR; ++m)
#pragma unroll
    for (int n = 0; n < 8; ++n) acc[m][n] = (f32x4){0.f, 0.f, 0.f, 0.f};

  auto stageA = [&](int slot, int kh, int tile) {
    int k0 = tile * 64 + kh * 32;
    constexpr int NLD = (BM * 32 * 2) / (512 * 16);
#pragma unroll
    for (int i = 0; i < NLD; ++i) {
      int c = i * 512 + wid * 64 + lane;
      int rg = c >> 2, cg = (c & 3) ^ (rg & 3);
      const unsigned short* g = A + (arow0 + rg) * K + k0 + cg * 8;
      GLOAD_LDS16(g, &As[slot][kh][c * 8]);
    }
  };
  auto stageB = [&](int slot, int kh, int tile) {
    int k0 = tile * 64 + kh * 32;
#pragma unroll
    for (int i = 0; i < 2; ++i) {
      int c = i * 512 + wid * 64 + lane;
      int rg = c >> 2, cg = (c & 3) ^ (rg & 3);
      const unsigned short* g = Bt + (brow0 + rg) * K + k0 + cg * 8;
      GLOAD_LDS16(g, &Bs[slot][kh][c * 8]);
    }
  };

  stageA(0, 0, 0); stageB(0, 0, 0); stageA(0, 1, 0); stageB(0, 1, 0);
  stageA(1, 0, 1); stageB(1, 0, 1); stageA(1, 1, 1);
  if constexpr (BM == 256) asm volatile("s_waitcnt vmcnt(6)" ::: "memory");
  else                     asm volatile("s_waitcnt vmcnt(4)" ::: "memory");
  __builtin_amdgcn_s_barrier();

  int NT2 = K / 128;
  for (int it = 0; it < NT2; ++it) {
    int t2 = it * 2;
#pragma unroll
    for (int tt = 0; tt < 2; ++tt) {
      bf16x8 af[MR];
#pragma unroll
      for (int kh = 0; kh < 2; ++kh) {
#pragma unroll
        for (int nh = 0; nh < 2; ++nh) {
          int p = tt * 4 + kh * 2 + nh + 1;
          if (nh == 0) {
#pragma unroll
            for (int m = 0; m < MR; ++m) {
              int r = wr * (MR * 16) + m * 16 + l15;
              af[m] = ldsread128(&As[tt][kh][r * 32 + ((l4 ^ (r & 3)) * 8)]);
            }
          }
          bf16x8 bf[4];
#pragma unroll
          for (int j = 0; j < 4; ++j) {
            int r = wc * 128 + (nh * 4 + j) * 16 + l15;
            bf[j] = ldsread128(&Bs[tt][kh][r * 32 + ((l4 ^ (r & 3)) * 8)]);
          }
          if (p == 1) stageB(1, 1, t2 + 1);
          if (p == 2) stageA(0, 0, t2 + 2 <= tmax ? t2 + 2 : tmax);
          if (p == 3) stageB(0, 0, t2 + 2 <= tmax ? t2 + 2 : tmax);
          if (p == 4) stageA(0, 1, t2 + 2 <= tmax ? t2 + 2 : tmax);
          if (p == 5) stageB(0, 1, t2 + 2 <= tmax ? t2 + 2 : tmax);
          if (p == 6) stageA(1, 0, t2 + 3 <= tmax ? t2 + 3 : tmax);
          if (p == 7) stageB(1, 0, t2 + 3 <= tmax ? t2 + 3 : tmax);
          if (p == 8) stageA(1, 1, t2 + 3 <= tmax ? t2 + 3 : tmax);

          __builtin_amdgcn_s_barrier();
          asm volatile("s_waitcnt lgkmcnt(0)" ::: "memory");
          __builtin_amdgcn_sched_barrier(0);
          __builtin_amdgcn_s_setprio(1);
#pragma unroll
          for (int m = 0; m < MR; ++m)
#pragma unroll
            for (int j = 0; j < 4; ++j)
              acc[m][nh * 4 + j] = __builtin_amdgcn_mfma_f32_16x16x32_bf16(
                  af[m], bf[j], acc[m][nh * 4 + j], 0, 0, 0);
          __builtin_amdgcn_s_setprio(0);
          if (p == 4 || p == 8) {
            if constexpr (BM == 256) asm volatile("s_waitcnt vmcnt(6)" ::: "memory");
            else                     asm volatile("s_waitcnt vmcnt(4)" ::: "memory");
          }
          __builtin_amdgcn_s_barrier();
        }
      }
    }
  }

  if constexpr (QKV) {
    int cb = (int)(brow0 + wc * 128);  // wave col base, head-aligned
    if (cb >= 2560) {
      // V head: write vt[(b*4+kvh)*128 + d][t] directly, ushort4 over r (4 consec t)
      int kvh = (cb - 2560) >> 7;
#pragma unroll
      for (int m = 0; m < MR; ++m) {
        size_t row0 = arow0 + wr * (MR * 16) + m * 16 + l4 * 4;
        int bb = (int)(row0 >> 11), t0 = (int)(row0 & (T_ - 1));
#pragma unroll
        for (int n = 0; n < 8; ++n) {
          int d = n * 16 + l15;
          ushort4 p4;
          p4.x = f2bf(acc[m][n][0]);
          p4.y = f2bf(acc[m][n][1]);
          p4.z = f2bf(acc[m][n][2]);
          p4.w = f2bf(acc[m][n][3]);
          *reinterpret_cast<ushort4*>(
              vtp + (size_t)((bb * 4 + kvh) * 128 + d) * T_ + t0) = p4;
        }
      }
    } else {
      // q/k: fused RoPE -> qkv
#pragma unroll
      for (int m = 0; m < MR; ++m)
#pragma unroll
        for (int r = 0; r < 4; ++r) {
          size_t row = arow0 + wr * (MR * 16) + m * 16 + l4 * 4 + r;
          int t = (int)(row & (T_ - 1));
#pragma unroll
          for (int n = 0; n < 4; ++n) {
            float2 cs = rt[t * 64 + n * 16 + l15];
            float a1 = acc[m][n][r], a2 = acc[m][n + 4][r];
            size_t col = brow0 + wc * 128 + n * 16 + l15;
            Cm[row * N + col]      = f2bf(a1 * cs.x - a2 * cs.y);
            Cm[row * N + col + 64] = f2bf(a2 * cs.x + a1 * cs.y);
          }
        }
    }
  } else {
#pragma unroll
    for (int m = 0; m < MR; ++m)
#pragma unroll
      for (int r = 0; r < 4; ++r) {
        size_t row = arow0 + wr * (MR * 16) + m * 16 + l4 * 4 + r;
#pragma unroll
        for (int n = 0; n < 8; ++n) {
          size_t col = brow0 + wc * 128 + n * 16 + l15;
          Cm[row * N + col] = acc[m][n][r];
        }
      }
  }
}

// ---------------- flash attention (R8 inner loop, KV-split scheduling — R15):
// 704 blocks, LPT order: qi 9,8 unsplit (longest) -> qi 15..10 split in two
// KV-halves (partial m/l/O output) -> qi 7..0 unsplit. Combine merges halves.
__global__ __launch_bounds__(256, 2) void attn_kernel(const unsigned short* __restrict__ qkv,
                                                      const unsigned short* __restrict__ vt,
                                                      unsigned short* __restrict__ att,
                                                      unsigned short* __restrict__ pO,
                                                      float2* __restrict__ ml) {
  constexpr int KB = 64;
  __shared__ __align__(16) unsigned short Kl[2][KB * 128];
  __shared__ __align__(16) unsigned short Vl[2][128 * KB];
  int tid = threadIdx.x, w = tid >> 6, lane = tid & 63;
  int l31 = lane & 31, hi = lane >> 5;
  int h4 = hi * 4;

  // LPT decode
  int id = blockIdx.x;
  int qi, bh, kt0, kt1, slot = -1;
  if (id < 64) {                       // unsplit qi 9,8 (longest items first)
    qi = 9 - (id >> 5); bh = id & 31; kt0 = 0; kt1 = 2 * qi + 2;
  } else if (id < 448) {               // split qi 15..10, two KV halves
    int s = id - 64;
    int pairidx = s >> 1, hihalf = s & 1;
    qi = 15 - (pairidx >> 5); bh = pairidx & 31;
    int nt = 2 * qi + 2, h = nt >> 1;
    kt0 = hihalf ? h : 0; kt1 = hihalf ? nt : h;
    slot = s;
  } else {                             // unsplit qi 7..0
    int u = id - 448;
    qi = 7 - (u >> 5); bh = u & 31; kt0 = 0; kt1 = 2 * qi + 2;
  }
  int q0 = qi * 128;
  int b = bh >> 4, hd = bh & 15, kvh = hd >> 2;
  int qr0 = q0 + w * 32;
  int ql = qr0 + l31;

  bf16x8 qf[8];
  {
    const unsigned short* qb = qkv + (size_t)(b * T_ + ql) * NQKV_ + hd * HD_ + hi * 8;
    const float scale = 0.08838834764831845f * 1.4426950408889634f;
#pragma unroll
    for (int df = 0; df < 8; ++df) {
      bf16x8 t = *reinterpret_cast<const bf16x8*>(qb + df * 16);
#pragma unroll
      for (int j = 0; j < 8; ++j) t[j] = (__bf16)((float)t[j] * scale);
      qf[df] = t;
    }
  }

  f32x16 o[4];
#pragma unroll
  for (int dt = 0; dt < 4; ++dt)
#pragma unroll
    for (int r = 0; r < 16; ++r) o[dt][r] = 0.f;
  float mr = -1e30f, lr = 0.f;

  auto stage = [&](int buf, int kv0) {
#pragma unroll
    for (int i = 0; i < 4; ++i) {
      int c = (i * 4 + w) * 64 + lane;
      int g = c ^ ((c >> 4) & 7);
      const unsigned short* src =
          qkv + (size_t)(b * T_ + kv0 + (g >> 4)) * NQKV_ + C_ + kvh * HD_ + (g & 15) * 8;
      GLOAD_LDS16(src, &Kl[buf][(i * 4 + w) * 512]);
    }
#pragma unroll
    for (int i = 0; i < 4; ++i) {
      int c = (i * 4 + w) * 64 + lane;
      int g = c ^ ((c >> 3) & 7);
      const unsigned short* src =
          vt + (size_t)((b * NKV_ + kvh) * HD_ + (g >> 3)) * T_ + kv0 + (g & 7) * 8;
      GLOAD_LDS16(src, &Vl[buf][(i * 4 + w) * 512]);
    }
  };

  stage(0, kt0 * KB);
  __syncthreads();
  int cur = 0;
  for (int kt = kt0; kt < kt1; ++kt) {
    int kv0 = kt * KB;
    if (kt + 1 < kt1) stage(cur ^ 1, kv0 + KB);

    if (kv0 <= qr0 + 31) {
      f32x16 s[2];
#pragma unroll
      for (int r = 0; r < 16; ++r) { s[0][r] = 0.f; s[1][r] = 0.f; }
      const unsigned short* Kb = &Kl[cur][0];
      __builtin_amdgcn_s_setprio(1);
#pragma unroll
      for (int t2 = 0; t2 < 2; ++t2)
#pragma unroll
        for (int df = 0; df < 8; ++df) {
          bf16x8 kf = *reinterpret_cast<const bf16x8*>(
              Kb + (((t2 * 32 + l31) * 128 + df * 16 + hi * 8) ^ ((l31 & 7) << 3)));
          s[t2] = __builtin_amdgcn_mfma_f32_32x32x16_bf16(kf, qf[df], s[t2], 0, 0, 0);
        }
      __builtin_amdgcn_s_setprio(0);

      float rm = -1e30f;
      if ((kv0 + KB - 1) > qr0) {
#pragma unroll
        for (int t2 = 0; t2 < 2; ++t2)
#pragma unroll
          for (int r = 0; r < 16; ++r) {
            float sv = s[t2][r];
            int kcol = kv0 + t2 * 32 + (r & 3) + 8 * (r >> 2) + h4;
            if (kcol > ql) sv = -1e30f;
            s[t2][r] = sv;
            rm = fmaxf(rm, sv);
          }
      } else {
#pragma unroll
        for (int t2 = 0; t2 < 2; ++t2)
#pragma unroll
          for (int r = 0; r < 16; ++r) rm = fmaxf(rm, s[t2][r]);
      }
      rm = fmaxf(rm, __shfl_xor(rm, 32));

      if (!__all(rm <= mr + 11.0f)) {
        float mnew = fmaxf(mr, rm);
        float alpha = exp2f(mr - mnew);
        mr = mnew;
        lr *= alpha;
#pragma unroll
        for (int dt = 0; dt < 4; ++dt)
#pragma unroll
          for (int r = 0; r < 16; ++r) o[dt][r] *= alpha;
      }

      float ps = 0.f;
#pragma unroll
      for (int t2 = 0; t2 < 2; ++t2)
#pragma unroll
        for (int r = 0; r < 16; ++r) {
          float p = exp2f(s[t2][r] - mr);
          s[t2][r] = p;
          ps += p;
        }
      lr += ps;

      unsigned pk[2][8];
#pragma unroll
      for (int t2 = 0; t2 < 2; ++t2)
#pragma unroll
        for (int i = 0; i < 8; ++i) {
          union { unsigned u32; __bf16 hh[2]; } pr;
          pr.hh[0] = (__bf16)s[t2][2 * i];
          pr.hh[1] = (__bf16)s[t2][2 * i + 1];
          pk[t2][i] = pr.u32;
        }

      bf16x8 pb[4];
#pragma unroll
      for (int f = 0; f < 4; ++f) {
        int t2 = f >> 1, bq = (f & 1) * 4;
        union { bf16x8 v; unsigned d[4]; } fr;
#pragma unroll
        for (int p = 0; p < 2; ++p) {
          unsigned uu = pk[t2][bq + p];
          unsigned ww = pk[t2][bq + 2 + p];
          unsigned us = (unsigned)__shfl_xor((int)uu, 32);
          unsigned ws = (unsigned)__shfl_xor((int)ww, 32);
          fr.d[p]     = hi ? ws : uu;
          fr.d[2 + p] = hi ? ww : us;
        }
        pb[f] = fr.v;
      }

      const unsigned short* Vb = &Vl[cur][0];
      __builtin_amdgcn_s_setprio(1);
#pragma unroll
      for (int dt = 0; dt < 4; ++dt)
#pragma unroll
        for (int kf = 0; kf < 4; ++kf) {
          bf16x8 vf = *reinterpret_cast<const bf16x8*>(
              Vb + (((dt * 32 + l31) * KB + kf * 16 + hi * 8) ^ ((l31 & 7) << 3)));
          o[dt] = __builtin_amdgcn_mfma_f32_32x32x16_bf16(vf, pb[kf], o[dt], 0, 0, 0);
        }
      __builtin_amdgcn_s_setprio(0);
    }

    __syncthreads();
    cur ^= 1;
  }

  float ls = lr + __shfl_xor(lr, 32);
  if (slot < 0) {
    float inv = 1.f / ls;
    unsigned short* ob = att + (size_t)(b * T_ + ql) * C_ + hd * HD_;
#pragma unroll
    for (int dt = 0; dt < 4; ++dt)
#pragma unroll
      for (int r = 0; r < 16; ++r) {
        int d = dt * 32 + (r & 3) + 8 * (r >> 2) + h4;
        ob[d] = f2bf(o[dt][r] * inv);
      }
  } else {
    int lrow = w * 32 + l31;
    unsigned short* po = pO + (size_t)slot * 16384 + lrow * 128;
#pragma unroll
    for (int dt = 0; dt < 4; ++dt)
#pragma unroll
      for (int r = 0; r < 16; ++r) {
        int d = dt * 32 + (r & 3) + 8 * (r >> 2) + h4;
        po[d] = f2bf(o[dt][r]);
      }
    if (hi == 0) ml[slot * 128 + lrow] = make_float2(mr, ls);
  }
}

// ---------------- merge KV-split halves: O = (w0*O0 + w1*O1) / (w0*l0 + w1*l1)
__global__ void combine_kernel(const unsigned short* __restrict__ pO,
                               const float2* __restrict__ ml,
                               unsigned short* __restrict__ att) {
  int pairidx = blockIdx.x;            // 0..191
  int qi = 15 - (pairidx >> 5), bh = pairidx & 31;
  int b = bh >> 4, hd = bh & 15;
  int q0 = qi * 128;
  int s0 = pairidx * 2, s1 = s0 + 1;
  int tid = threadIdx.x;               // 256: 2 threads per row, 64 d each
  int row = tid >> 1, dh = (tid & 1) * 64;
  float2 ml0 = ml[s0 * 128 + row], ml1 = ml[s1 * 128 + row];
  float m = fmaxf(ml0.x, ml1.x);
  float w0 = exp2f(ml0.x - m), w1 = exp2f(ml1.x - m);
  float inv = 1.f / (w0 * ml0.y + w1 * ml1.y);
  const unsigned short* p0 = pO + (size_t)s0 * 16384 + row * 128 + dh;
  const unsigned short* p1 = pO + (size_t)s1 * 16384 + row * 128 + dh;
  unsigned short* ob = att + (size_t)(b * T_ + q0 + row) * C_ + hd * HD_ + dh;
#pragma unroll
  for (int j = 0; j < 64; j += 4) {
    ushort4 a = *reinterpret_cast<const ushort4*>(p0 + j);
    ushort4 c = *reinterpret_cast<const ushort4*>(p1 + j);
    ushort4 r;
    r.x = f2bf((w0 * bf2f(a.x) + w1 * bf2f(c.x)) * inv);
    r.y = f2bf((w0 * bf2f(a.y) + w1 * bf2f(c.y)) * inv);
    r.z = f2bf((w0 * bf2f(a.z) + w1 * bf2f(c.z)) * inv);
    r.w = f2bf((w0 * bf2f(a.w) + w1 * bf2f(c.w)) * inv);
    *reinterpret_cast<ushort4*>(ob + j) = r;
  }
}

extern "C" void kernel_launch(void* const* d_in, const int* in_sizes, int n_in,
                              void* d_out, int out_size, void* d_ws, size_t ws_size,
                              hipStream_t stream) {
  const float* x  = (const float*)d_in[0];
  const float* Wq = (const float*)d_in[1];
  const float* Wk = (const float*)d_in[2];
  const float* Wv = (const float*)d_in[3];
  const float* Wp = (const float*)d_in[4];
  float* out = (float*)d_out;
  char* ws = (char*)d_ws;

  // workspace layout (bytes); total 68,157,440
  unsigned short* xb  = (unsigned short*)(ws);              // 16MB  x bf16 (att aliases)
  unsigned short* wt  = (unsigned short*)(ws + 16777216);   // 20MB  Wq^T|Wk^T|Wv^T|Wp^T
  unsigned short* qkv = (unsigned short*)(ws + 37748736);   // 24MB  q(rope)|k(rope)|(v unused)
  float2*         rt  = (float2*)(ws + 62914560);           // 1MB   cos/sin (dead after GEMM1)
  unsigned short* vt  = (unsigned short*)(ws + 63963136);   // 4MB   V d-major [bh*HD+d][t]
  unsigned short* att = xb;                                 // alias: xb dead after GEMM1
  unsigned short* pO  = wt;                                 // alias: Wq/k/v^T dead after GEMM1
  float2*         ml  = rt;                                 // alias: rt dead after GEMM1

  prep_kernel<<<dim3(18944), 256, 0, stream>>>(x, Wq, Wk, Wv, Wp, xb, wt, rt);

  gemm8p<256, unsigned short, true><<<dim3(NQKV_ / 256, M_ / 256), 512, 0, stream>>>(
      xb, wt, qkv, vt, rt, M_, NQKV_, C_);
  attn_kernel<<<dim3(704), 256, 0, stream>>>(qkv, vt, att, pO, ml);
  combine_kernel<<<dim3(192), 256, 0, stream>>>(pO, ml, att);
  gemm8p<128, float, false><<<dim3(C_ / 256, M_ / 128), 512, 0, stream>>>(
      att, wt + (size_t)3072 * 2048, out, nullptr, nullptr, M_, C_, C_);
}

// Round 21
// 211.603 us; speedup vs baseline: 1.3351x; 1.0031x over previous
//
#include <hip/hip_runtime.h>

#define B_ 2
#define T_ 2048
#define C_ 2048
#define NH_ 16
#define NKV_ 4
#define HD_ 128
#define M_ 4096          // B*T
#define NQKV_ 3072

typedef __bf16 bf16x8 __attribute__((ext_vector_type(8)));
typedef float f32x4 __attribute__((ext_vector_type(4)));
typedef float f32x16 __attribute__((ext_vector_type(16)));

__device__ __forceinline__ unsigned short f2bf(float f) {
  union { float f; unsigned u; } c{f};
  unsigned u = c.u + 0x7FFFu + ((c.u >> 16) & 1u);
  return (unsigned short)(u >> 16);
}
__device__ __forceinline__ float bf2f(unsigned short h) {
  union { unsigned u; float f; } c{(unsigned)h << 16};
  return c.f;
}

#define GLOAD_LDS16(g, l)                                        \
  __builtin_amdgcn_global_load_lds(                              \
      (const __attribute__((address_space(1))) void*)(g),        \
      (__attribute__((address_space(3))) void*)(l), 16, 0, 0)

// asm ds_read_b128 (rule #18: fence with lgkmcnt(0)+sched_barrier(0) before use)
__device__ __forceinline__ bf16x8 ldsread128(const unsigned short* p) {
  uint4 d;
  asm volatile("ds_read_b128 %0, %1"
               : "=v"(d)
               : "v"((const __attribute__((address_space(3))) void*)p));
  union { uint4 u; bf16x8 v; } c;
  c.u = d;
  return c.v;
}

// ---------------- fused prep: weight transposes (64x64 tiles, wide coalescing)
// + x->bf16 + rope table
__global__ void prep_kernel(const float* __restrict__ x, const float* __restrict__ Wq,
                            const float* __restrict__ Wk, const float* __restrict__ Wv,
                            const float* __restrict__ Wp, unsigned short* __restrict__ xb,
                            unsigned short* __restrict__ wt, float2* __restrict__ rt) {
  int id = blockIdx.x;
  int t = threadIdx.x;
  if (id < 2560) {  // weight transpose-convert, 64x64 tile
    __shared__ float tile[64][65];
    const float* W;
    unsigned short* Wt;
    int N, bx, by;
    if (id < 1024)      { W = Wq; Wt = wt;                       N = 2048; int u = id;        bx = u & 31; by = u >> 5; }
    else if (id < 1280) { W = Wk; Wt = wt + (size_t)2048 * 2048; N = 512;  int u = id - 1024; bx = u & 7;  by = u >> 3; }
    else if (id < 1536) { W = Wv; Wt = wt + (size_t)2560 * 2048; N = 512;  int u = id - 1280; bx = u & 7;  by = u >> 3; }
    else                { W = Wp; Wt = wt + (size_t)3072 * 2048; N = 2048; int u = id - 1536; bx = u & 31; by = u >> 5; }
    const int K = 2048;
    bx *= 64; by *= 64;
    int n = t & 63, k4 = t >> 6;  // read: 4 k-rows in flight, 256B rows
#pragma unroll
    for (int r = 0; r < 16; ++r)
      tile[k4 + r * 4][n] = W[(size_t)(by + k4 + r * 4) * N + bx + n];
    __syncthreads();
    int nw = t >> 2, kb = (t & 3) * 16;  // write: 16 consecutive k per thread (32B)
    unsigned short tmp[16];
#pragma unroll
    for (int j = 0; j < 16; ++j) tmp[j] = f2bf(tile[kb + j][nw]);
    unsigned short* dst = Wt + (size_t)(bx + nw) * K + by + kb;
#pragma unroll
    for (int j = 0; j < 2; ++j)
      *reinterpret_cast<uint4*>(dst + j * 8) = reinterpret_cast<uint4*>(tmp)[j];
  } else if (id < 10752) {  // x f32 -> bf16, float4 chunks
    int i = (id - 2560) * 256 + t;
    float4 v = reinterpret_cast<const float4*>(x)[i];
    union { ushort4 u; unsigned short s[4]; } o;
    o.s[0] = f2bf(v.x); o.s[1] = f2bf(v.y); o.s[2] = f2bf(v.z); o.s[3] = f2bf(v.w);
    reinterpret_cast<ushort4*>(xb)[i] = o.u;
  } else {  // rope table
    int g = (id - 10752) * 256 + t;
    int tt = g >> 6, i = g & 63;
    float inv = powf(10000.f, -(float)(2 * i) / 128.f);
    float s, c;
    sincosf((float)tt * inv, &s, &c);
    rt[tt * 64 + i] = make_float2(c, s);
  }
}

// ---------------- 8-phase bf16 GEMM (T3+T4+T5), asm ds_read (R14, proven).
// QKV=true epilogue: q,k -> rope -> qkv; V head-blocks -> vt d-major directly.
template <int BM, typename OUT, bool QKV>
__global__ __launch_bounds__(512, 1) void gemm8p(const unsigned short* __restrict__ A,
                                                 const unsigned short* __restrict__ Bt,
                                                 OUT* __restrict__ Cm,
                                                 unsigned short* __restrict__ vtp,
                                                 const float2* __restrict__ rt,
                                                 int M, int N, int K) {
  constexpr int MR = BM / 64;
  __shared__ __align__(16) unsigned short As[2][2][BM * 32];
  __shared__ __align__(16) unsigned short Bs[2][2][256 * 32];
  int tid = threadIdx.x, wid = tid >> 6, lane = tid & 63;
  int l15 = lane & 15, l4 = lane >> 4;
  int wr = wid >> 1, wc = wid & 1;
  size_t arow0 = (size_t)blockIdx.y * BM;
  size_t brow0 = (size_t)blockIdx.x * 256;
  int tmax = K / 64 - 1;

  f32x4 acc[MR][8];
#pragma unroll
  for (int m = 0; m < MR; ++m)
#pragma unroll
    for (int n = 0; n < 8; ++n) acc[m][n] = (f32x4){0.f, 0.f, 0.f, 0.f};

  auto stageA = [&](int slot, int kh, int tile) {
    int k0 = tile * 64 + kh * 32;
    constexpr int NLD = (BM * 32 * 2) / (512 * 16);
#pragma unroll
    for (int i = 0; i < NLD; ++i) {
      int c = i * 512 + wid * 64 + lane;
      int rg = c >> 2, cg = (c & 3) ^ (rg & 3);
      const unsigned short* g = A + (arow0 + rg) * K + k0 + cg * 8;
      GLOAD_LDS16(g, &As[slot][kh][c * 8]);
    }
  };
  auto stageB = [&](int slot, int kh, int tile) {
    int k0 = tile * 64 + kh * 32;
#pragma unroll
    for (int i = 0; i < 2; ++i) {
      int c = i * 512 + wid * 64 + lane;
      int rg = c >> 2, cg = (c & 3) ^ (rg & 3);
      const unsigned short* g = Bt + (brow0 + rg) * K + k0 + cg * 8;
      GLOAD_LDS16(g, &Bs[slot][kh][c * 8]);
    }
  };

  stageA(0, 0, 0); stageB(0, 0, 0); stageA(0, 1, 0); stageB(0, 1, 0);
  stageA(1, 0, 1); stageB(1, 0, 1); stageA(1, 1, 1);
  if constexpr (BM == 256) asm volatile("s_waitcnt vmcnt(6)" ::: "memory");
  else                     asm volatile("s_waitcnt vmcnt(4)" ::: "memory");
  __builtin_amdgcn_s_barrier();

  int NT2 = K / 128;
  for (int it = 0; it < NT2; ++it) {
    int t2 = it * 2;
#pragma unroll
    for (int tt = 0; tt < 2; ++tt) {
      bf16x8 af[MR];
#pragma unroll
      for (int kh = 0; kh < 2; ++kh) {
#pragma unroll
        for (int nh = 0; nh < 2; ++nh) {
          int p = tt * 4 + kh * 2 + nh + 1;
          if (nh == 0) {
#pragma unroll
            for (int m = 0; m < MR; ++m) {
              int r = wr * (MR * 16) + m * 16 + l15;
              af[m] = ldsread128(&As[tt][kh][r * 32 + ((l4 ^ (r & 3)) * 8)]);
            }
          }
          bf16x8 bf[4];
#pragma unroll
          for (int j = 0; j < 4; ++j) {
            int r = wc * 128 + (nh * 4 + j) * 16 + l15;
            bf[j] = ldsread128(&Bs[tt][kh][r * 32 + ((l4 ^ (r & 3)) * 8)]);
          }
          if (p == 1) stageB(1, 1, t2 + 1);
          if (p == 2) stageA(0, 0, t2 + 2 <= tmax ? t2 + 2 : tmax);
          if (p == 3) stageB(0, 0, t2 + 2 <= tmax ? t2 + 2 : tmax);
          if (p == 4) stageA(0, 1, t2 + 2 <= tmax ? t2 + 2 : tmax);
          if (p == 5) stageB(0, 1, t2 + 2 <= tmax ? t2 + 2 : tmax);
          if (p == 6) stageA(1, 0, t2 + 3 <= tmax ? t2 + 3 : tmax);
          if (p == 7) stageB(1, 0, t2 + 3 <= tmax ? t2 + 3 : tmax);
          if (p == 8) stageA(1, 1, t2 + 3 <= tmax ? t2 + 3 : tmax);

          __builtin_amdgcn_s_barrier();
          asm volatile("s_waitcnt lgkmcnt(0)" ::: "memory");
          __builtin_amdgcn_sched_barrier(0);
          __builtin_amdgcn_s_setprio(1);
#pragma unroll
          for (int m = 0; m < MR; ++m)
#pragma unroll
            for (int j = 0; j < 4; ++j)
              acc[m][nh * 4 + j] = __builtin_amdgcn_mfma_f32_16x16x32_bf16(
                  af[m], bf[j], acc[m][nh * 4 + j], 0, 0, 0);
          __builtin_amdgcn_s_setprio(0);
          if (p == 4 || p == 8) {
            if constexpr (BM == 256) asm volatile("s_waitcnt vmcnt(6)" ::: "memory");
            else                     asm volatile("s_waitcnt vmcnt(4)" ::: "memory");
          }
          __builtin_amdgcn_s_barrier();
        }
      }
    }
  }

  if constexpr (QKV) {
    int cb = (int)(brow0 + wc * 128);  // wave col base, head-aligned
    if (cb >= 2560) {
      // V head: write vt[(b*4+kvh)*128 + d][t] directly, ushort4 over r (4 consec t)
      int kvh = (cb - 2560) >> 7;
#pragma unroll
      for (int m = 0; m < MR; ++m) {
        size_t row0 = arow0 + wr * (MR * 16) + m * 16 + l4 * 4;
        int bb = (int)(row0 >> 11), t0 = (int)(row0 & (T_ - 1));
#pragma unroll
        for (int n = 0; n < 8; ++n) {
          int d = n * 16 + l15;
          ushort4 p4;
          p4.x = f2bf(acc[m][n][0]);
          p4.y = f2bf(acc[m][n][1]);
          p4.z = f2bf(acc[m][n][2]);
          p4.w = f2bf(acc[m][n][3]);
          *reinterpret_cast<ushort4*>(
              vtp + (size_t)((bb * 4 + kvh) * 128 + d) * T_ + t0) = p4;
        }
      }
    } else {
      // q/k: fused RoPE -> qkv
#pragma unroll
      for (int m = 0; m < MR; ++m)
#pragma unroll
        for (int r = 0; r < 4; ++r) {
          size_t row = arow0 + wr * (MR * 16) + m * 16 + l4 * 4 + r;
          int t = (int)(row & (T_ - 1));
#pragma unroll
          for (int n = 0; n < 4; ++n) {
            float2 cs = rt[t * 64 + n * 16 + l15];
            float a1 = acc[m][n][r], a2 = acc[m][n + 4][r];
            size_t col = brow0 + wc * 128 + n * 16 + l15;
            Cm[row * N + col]      = f2bf(a1 * cs.x - a2 * cs.y);
            Cm[row * N + col + 64] = f2bf(a2 * cs.x + a1 * cs.y);
          }
        }
    }
  } else {
#pragma unroll
    for (int m = 0; m < MR; ++m)
#pragma unroll
      for (int r = 0; r < 4; ++r) {
        size_t row = arow0 + wr * (MR * 16) + m * 16 + l4 * 4 + r;
#pragma unroll
        for (int n = 0; n < 8; ++n) {
          size_t col = brow0 + wc * 128 + n * 16 + l15;
          Cm[row * N + col] = acc[m][n][r];
        }
      }
  }
}

// ---------------- flash attention (R8 inner loop, KV-split scheduling — R15):
// 704 blocks, LPT order: qi 9,8 unsplit (longest) -> qi 15..10 split in two
// KV-halves (partial m/l/O output) -> qi 7..0 unsplit. Combine merges halves.
__global__ __launch_bounds__(256, 2) void attn_kernel(const unsigned short* __restrict__ qkv,
                                                      const unsigned short* __restrict__ vt,
                                                      unsigned short* __restrict__ att,
                                                      unsigned short* __restrict__ pO,
                                                      float2* __restrict__ ml) {
  constexpr int KB = 64;
  __shared__ __align__(16) unsigned short Kl[2][KB * 128];
  __shared__ __align__(16) unsigned short Vl[2][128 * KB];
  int tid = threadIdx.x, w = tid >> 6, lane = tid & 63;
  int l31 = lane & 31, hi = lane >> 5;
  int h4 = hi * 4;

  // LPT decode
  int id = blockIdx.x;
  int qi, bh, kt0, kt1, slot = -1;
  if (id < 64) {                       // unsplit qi 9,8 (longest items first)
    qi = 9 - (id >> 5); bh = id & 31; kt0 = 0; kt1 = 2 * qi + 2;
  } else if (id < 448) {               // split qi 15..10, two KV halves
    int s = id - 64;
    int pairidx = s >> 1, hihalf = s & 1;
    qi = 15 - (pairidx >> 5); bh = pairidx & 31;
    int nt = 2 * qi + 2, h = nt >> 1;
    kt0 = hihalf ? h : 0; kt1 = hihalf ? nt : h;
    slot = s;
  } else {                             // unsplit qi 7..0
    int u = id - 448;
    qi = 7 - (u >> 5); bh = u & 31; kt0 = 0; kt1 = 2 * qi + 2;
  }
  int q0 = qi * 128;
  int b = bh >> 4, hd = bh & 15, kvh = hd >> 2;
  int qr0 = q0 + w * 32;
  int ql = qr0 + l31;

  bf16x8 qf[8];
  {
    const unsigned short* qb = qkv + (size_t)(b * T_ + ql) * NQKV_ + hd * HD_ + hi * 8;
    const float scale = 0.08838834764831845f * 1.4426950408889634f;
#pragma unroll
    for (int df = 0; df < 8; ++df) {
      bf16x8 t = *reinterpret_cast<const bf16x8*>(qb + df * 16);
#pragma unroll
      for (int j = 0; j < 8; ++j) t[j] = (__bf16)((float)t[j] * scale);
      qf[df] = t;
    }
  }

  f32x16 o[4];
#pragma unroll
  for (int dt = 0; dt < 4; ++dt)
#pragma unroll
    for (int r = 0; r < 16; ++r) o[dt][r] = 0.f;
  float mr = -1e30f, lr = 0.f;

  auto stage = [&](int buf, int kv0) {
#pragma unroll
    for (int i = 0; i < 4; ++i) {
      int c = (i * 4 + w) * 64 + lane;
      int g = c ^ ((c >> 4) & 7);
      const unsigned short* src =
          qkv + (size_t)(b * T_ + kv0 + (g >> 4)) * NQKV_ + C_ + kvh * HD_ + (g & 15) * 8;
      GLOAD_LDS16(src, &Kl[buf][(i * 4 + w) * 512]);
    }
#pragma unroll
    for (int i = 0; i < 4; ++i) {
      int c = (i * 4 + w) * 64 + lane;
      int g = c ^ ((c >> 3) & 7);
      const unsigned short* src =
          vt + (size_t)((b * NKV_ + kvh) * HD_ + (g >> 3)) * T_ + kv0 + (g & 7) * 8;
      GLOAD_LDS16(src, &Vl[buf][(i * 4 + w) * 512]);
    }
  };

  stage(0, kt0 * KB);
  __syncthreads();
  int cur = 0;
  for (int kt = kt0; kt < kt1; ++kt) {
    int kv0 = kt * KB;
    if (kt + 1 < kt1) stage(cur ^ 1, kv0 + KB);

    if (kv0 <= qr0 + 31) {
      f32x16 s[2];
#pragma unroll
      for (int r = 0; r < 16; ++r) { s[0][r] = 0.f; s[1][r] = 0.f; }
      const unsigned short* Kb = &Kl[cur][0];
      __builtin_amdgcn_s_setprio(1);
#pragma unroll
      for (int t2 = 0; t2 < 2; ++t2)
#pragma unroll
        for (int df = 0; df < 8; ++df) {
          bf16x8 kf = *reinterpret_cast<const bf16x8*>(
              Kb + (((t2 * 32 + l31) * 128 + df * 16 + hi * 8) ^ ((l31 & 7) << 3)));
          s[t2] = __builtin_amdgcn_mfma_f32_32x32x16_bf16(kf, qf[df], s[t2], 0, 0, 0);
        }
      __builtin_amdgcn_s_setprio(0);

      float rm = -1e30f;
      if ((kv0 + KB - 1) > qr0) {
#pragma unroll
        for (int t2 = 0; t2 < 2; ++t2)
#pragma unroll
          for (int r = 0; r < 16; ++r) {
            float sv = s[t2][r];
            int kcol = kv0 + t2 * 32 + (r & 3) + 8 * (r >> 2) + h4;
            if (kcol > ql) sv = -1e30f;
            s[t2][r] = sv;
            rm = fmaxf(rm, sv);
          }
      } else {
#pragma unroll
        for (int t2 = 0; t2 < 2; ++t2)
#pragma unroll
          for (int r = 0; r < 16; ++r) rm = fmaxf(rm, s[t2][r]);
      }
      rm = fmaxf(rm, __shfl_xor(rm, 32));

      if (!__all(rm <= mr + 11.0f)) {
        float mnew = fmaxf(mr, rm);
        float alpha = exp2f(mr - mnew);
        mr = mnew;
        lr *= alpha;
#pragma unroll
        for (int dt = 0; dt < 4; ++dt)
#pragma unroll
          for (int r = 0; r < 16; ++r) o[dt][r] *= alpha;
      }

      float ps = 0.f;
#pragma unroll
      for (int t2 = 0; t2 < 2; ++t2)
#pragma unroll
        for (int r = 0; r < 16; ++r) {
          float p = exp2f(s[t2][r] - mr);
          s[t2][r] = p;
          ps += p;
        }
      lr += ps;

      unsigned pk[2][8];
#pragma unroll
      for (int t2 = 0; t2 < 2; ++t2)
#pragma unroll
        for (int i = 0; i < 8; ++i) {
          union { unsigned u32; __bf16 hh[2]; } pr;
          pr.hh[0] = (__bf16)s[t2][2 * i];
          pr.hh[1] = (__bf16)s[t2][2 * i + 1];
          pk[t2][i] = pr.u32;
        }

      bf16x8 pb[4];
#pragma unroll
      for (int f = 0; f < 4; ++f) {
        int t2 = f >> 1, bq = (f & 1) * 4;
        union { bf16x8 v; unsigned d[4]; } fr;
#pragma unroll
        for (int p = 0; p < 2; ++p) {
          unsigned uu = pk[t2][bq + p];
          unsigned ww = pk[t2][bq + 2 + p];
          unsigned us = (unsigned)__shfl_xor((int)uu, 32);
          unsigned ws = (unsigned)__shfl_xor((int)ww, 32);
          fr.d[p]     = hi ? ws : uu;
          fr.d[2 + p] = hi ? ww : us;
        }
        pb[f] = fr.v;
      }

      const unsigned short* Vb = &Vl[cur][0];
      __builtin_amdgcn_s_setprio(1);
#pragma unroll
      for (int dt = 0; dt < 4; ++dt)
#pragma unroll
        for (int kf = 0; kf < 4; ++kf) {
          bf16x8 vf = *reinterpret_cast<const bf16x8*>(
              Vb + (((dt * 32 + l31) * KB + kf * 16 + hi * 8) ^ ((l31 & 7) << 3)));
          o[dt] = __builtin_amdgcn_mfma_f32_32x32x16_bf16(vf, pb[kf], o[dt], 0, 0, 0);
        }
      __builtin_amdgcn_s_setprio(0);
    }

    __syncthreads();
    cur ^= 1;
  }

  float ls = lr + __shfl_xor(lr, 32);
  if (slot < 0) {
    float inv = 1.f / ls;
    unsigned short* ob = att + (size_t)(b * T_ + ql) * C_ + hd * HD_;
#pragma unroll
    for (int dt = 0; dt < 4; ++dt)
#pragma unroll
      for (int r = 0; r < 16; ++r) {
        int d = dt * 32 + (r & 3) + 8 * (r >> 2) + h4;
        ob[d] = f2bf(o[dt][r] * inv);
      }
  } else {
    int lrow = w * 32 + l31;
    unsigned short* po = pO + (size_t)slot * 16384 + lrow * 128;
#pragma unroll
    for (int dt = 0; dt < 4; ++dt)
#pragma unroll
      for (int r = 0; r < 16; ++r) {
        int d = dt * 32 + (r & 3) + 8 * (r >> 2) + h4;
        po[d] = f2bf(o[dt][r]);
      }
    if (hi == 0) ml[slot * 128 + lrow] = make_float2(mr, ls);
  }
}

// ---------------- merge KV-split halves: O = (w0*O0 + w1*O1) / (w0*l0 + w1*l1)
__global__ void combine_kernel(const unsigned short* __restrict__ pO,
                               const float2* __restrict__ ml,
                               unsigned short* __restrict__ att) {
  int pairidx = blockIdx.x;            // 0..191
  int qi = 15 - (pairidx >> 5), bh = pairidx & 31;
  int b = bh >> 4, hd = bh & 15;
  int q0 = qi * 128;
  int s0 = pairidx * 2, s1 = s0 + 1;
  int tid = threadIdx.x;               // 256: 2 threads per row, 64 d each
  int row = tid >> 1, dh = (tid & 1) * 64;
  float2 ml0 = ml[s0 * 128 + row], ml1 = ml[s1 * 128 + row];
  float m = fmaxf(ml0.x, ml1.x);
  float w0 = exp2f(ml0.x - m), w1 = exp2f(ml1.x - m);
  float inv = 1.f / (w0 * ml0.y + w1 * ml1.y);
  const unsigned short* p0 = pO + (size_t)s0 * 16384 + row * 128 + dh;
  const unsigned short* p1 = pO + (size_t)s1 * 16384 + row * 128 + dh;
  unsigned short* ob = att + (size_t)(b * T_ + q0 + row) * C_ + hd * HD_ + dh;
#pragma unroll
  for (int j = 0; j < 64; j += 4) {
    ushort4 a = *reinterpret_cast<const ushort4*>(p0 + j);
    ushort4 c = *reinterpret_cast<const ushort4*>(p1 + j);
    ushort4 r;
    r.x = f2bf((w0 * bf2f(a.x) + w1 * bf2f(c.x)) * inv);
    r.y = f2bf((w0 * bf2f(a.y) + w1 * bf2f(c.y)) * inv);
    r.z = f2bf((w0 * bf2f(a.z) + w1 * bf2f(c.z)) * inv);
    r.w = f2bf((w0 * bf2f(a.w) + w1 * bf2f(c.w)) * inv);
    *reinterpret_cast<ushort4*>(ob + j) = r;
  }
}

extern "C" void kernel_launch(void* const* d_in, const int* in_sizes, int n_in,
                              void* d_out, int out_size, void* d_ws, size_t ws_size,
                              hipStream_t stream) {
  const float* x  = (const float*)d_in[0];
  const float* Wq = (const float*)d_in[1];
  const float* Wk = (const float*)d_in[2];
  const float* Wv = (const float*)d_in[3];
  const float* Wp = (const float*)d_in[4];
  float* out = (float*)d_out;
  char* ws = (char*)d_ws;

  // workspace layout (bytes); total 68,157,440
  unsigned short* xb  = (unsigned short*)(ws);              // 16MB  x bf16 (att aliases)
  unsigned short* wt  = (unsigned short*)(ws + 16777216);   // 20MB  Wq^T|Wk^T|Wv^T|Wp^T
  unsigned short* qkv = (unsigned short*)(ws + 37748736);   // 24MB  q(rope)|k(rope)|(v unused)
  float2*         rt  = (float2*)(ws + 62914560);           // 1MB   cos/sin (dead after GEMM1)
  unsigned short* vt  = (unsigned short*)(ws + 63963136);   // 4MB   V d-major [bh*HD+d][t]
  unsigned short* att = xb;                                 // alias: xb dead after GEMM1
  unsigned short* pO  = wt;                                 // alias: Wq/k/v^T dead after GEMM1
  float2*         ml  = rt;                                 // alias: rt dead after GEMM1

  prep_kernel<<<dim3(11264), 256, 0, stream>>>(x, Wq, Wk, Wv, Wp, xb, wt, rt);

  gemm8p<256, unsigned short, true><<<dim3(NQKV_ / 256, M_ / 256), 512, 0, stream>>>(
      xb, wt, qkv, vt, rt, M_, NQKV_, C_);
  attn_kernel<<<dim3(704), 256, 0, stream>>>(qkv, vt, att, pO, ml);
  combine_kernel<<<dim3(192), 256, 0, stream>>>(pO, ml, att);
  gemm8p<128, float, false><<<dim3(C_ / 256, M_ / 128), 512, 0, stream>>>(
      att, wt + (size_t)3072 * 2048, out, nullptr, nullptr, M_, C_, C_);
}

// Round 22
// 210.124 us; speedup vs baseline: 1.3445x; 1.0070x over previous
//
#include <hip/hip_runtime.h>

#define B_ 2
#define T_ 2048
#define C_ 2048
#define NH_ 16
#define NKV_ 4
#define HD_ 128
#define M_ 4096          // B*T
#define NQKV_ 3072

typedef __bf16 bf16x8 __attribute__((ext_vector_type(8)));
typedef float f32x4 __attribute__((ext_vector_type(4)));
typedef float f32x16 __attribute__((ext_vector_type(16)));

__device__ __forceinline__ unsigned short f2bf(float f) {
  union { float f; unsigned u; } c{f};
  unsigned u = c.u + 0x7FFFu + ((c.u >> 16) & 1u);
  return (unsigned short)(u >> 16);
}
__device__ __forceinline__ float bf2f(unsigned short h) {
  union { unsigned u; float f; } c{(unsigned)h << 16};
  return c.f;
}

#define GLOAD_LDS16(g, l)                                        \
  __builtin_amdgcn_global_load_lds(                              \
      (const __attribute__((address_space(1))) void*)(g),        \
      (__attribute__((address_space(3))) void*)(l), 16, 0, 0)

// asm ds_read_b128 (rule #18: fence with lgkmcnt(0)+sched_barrier(0) before use)
__device__ __forceinline__ bf16x8 ldsread128(const unsigned short* p) {
  uint4 d;
  asm volatile("ds_read_b128 %0, %1"
               : "=v"(d)
               : "v"((const __attribute__((address_space(3))) void*)p));
  union { uint4 u; bf16x8 v; } c;
  c.u = d;
  return c.v;
}

// ---------------- fused prep: weight transposes (64x64 tiles) + x->bf16 + rope
__global__ void prep_kernel(const float* __restrict__ x, const float* __restrict__ Wq,
                            const float* __restrict__ Wk, const float* __restrict__ Wv,
                            const float* __restrict__ Wp, unsigned short* __restrict__ xb,
                            unsigned short* __restrict__ wt, float2* __restrict__ rt) {
  int id = blockIdx.x;
  int t = threadIdx.x;
  if (id < 2560) {  // weight transpose-convert, 64x64 tile
    __shared__ float tile[64][65];
    const float* W;
    unsigned short* Wt;
    int N, bx, by;
    if (id < 1024)      { W = Wq; Wt = wt;                       N = 2048; int u = id;        bx = u & 31; by = u >> 5; }
    else if (id < 1280) { W = Wk; Wt = wt + (size_t)2048 * 2048; N = 512;  int u = id - 1024; bx = u & 7;  by = u >> 3; }
    else if (id < 1536) { W = Wv; Wt = wt + (size_t)2560 * 2048; N = 512;  int u = id - 1280; bx = u & 7;  by = u >> 3; }
    else                { W = Wp; Wt = wt + (size_t)3072 * 2048; N = 2048; int u = id - 1536; bx = u & 31; by = u >> 5; }
    const int K = 2048;
    bx *= 64; by *= 64;
    int n = t & 63, k4 = t >> 6;
#pragma unroll
    for (int r = 0; r < 16; ++r)
      tile[k4 + r * 4][n] = W[(size_t)(by + k4 + r * 4) * N + bx + n];
    __syncthreads();
    int nw = t >> 2, kb = (t & 3) * 16;
    unsigned short tmp[16];
#pragma unroll
    for (int j = 0; j < 16; ++j) tmp[j] = f2bf(tile[kb + j][nw]);
    unsigned short* dst = Wt + (size_t)(bx + nw) * K + by + kb;
#pragma unroll
    for (int j = 0; j < 2; ++j)
      *reinterpret_cast<uint4*>(dst + j * 8) = reinterpret_cast<uint4*>(tmp)[j];
  } else if (id < 10752) {  // x f32 -> bf16
    int i = (id - 2560) * 256 + t;
    float4 v = reinterpret_cast<const float4*>(x)[i];
    union { ushort4 u; unsigned short s[4]; } o;
    o.s[0] = f2bf(v.x); o.s[1] = f2bf(v.y); o.s[2] = f2bf(v.z); o.s[3] = f2bf(v.w);
    reinterpret_cast<ushort4*>(xb)[i] = o.u;
  } else {  // rope table
    int g = (id - 10752) * 256 + t;
    int tt = g >> 6, i = g & 63;
    float inv = powf(10000.f, -(float)(2 * i) / 128.f);
    float s, c;
    sincosf((float)tt * inv, &s, &c);
    rt[tt * 64 + i] = make_float2(c, s);
  }
}

// ---------------- 8-phase bf16 GEMM (T3+T4+T5), asm ds_read (R14, proven).
// QKV=true epilogue: q,k -> rope -> qkv; V head-blocks -> vt d-major directly.
template <int BM, typename OUT, bool QKV>
__global__ __launch_bounds__(512, 1) void gemm8p(const unsigned short* __restrict__ A,
                                                 const unsigned short* __restrict__ Bt,
                                                 OUT* __restrict__ Cm,
                                                 unsigned short* __restrict__ vtp,
                                                 const float2* __restrict__ rt,
                                                 int M, int N, int K) {
  constexpr int MR = BM / 64;
  __shared__ __align__(16) unsigned short As[2][2][BM * 32];
  __shared__ __align__(16) unsigned short Bs[2][2][256 * 32];
  int tid = threadIdx.x, wid = tid >> 6, lane = tid & 63;
  int l15 = lane & 15, l4 = lane >> 4;
  int wr = wid >> 1, wc = wid & 1;
  size_t arow0 = (size_t)blockIdx.y * BM;
  size_t brow0 = (size_t)blockIdx.x * 256;
  int tmax = K / 64 - 1;

  f32x4 acc[MR][8];
#pragma unroll
  for (int m = 0; m < MR; ++m)
#pragma unroll
    for (int n = 0; n < 8; ++n) acc[m][n] = (f32x4){0.f, 0.f, 0.f, 0.f};

  auto stageA = [&](int slot, int kh, int tile) {
    int k0 = tile * 64 + kh * 32;
    constexpr int NLD = (BM * 32 * 2) / (512 * 16);
#pragma unroll
    for (int i = 0; i < NLD; ++i) {
      int c = i * 512 + wid * 64 + lane;
      int rg = c >> 2, cg = (c & 3) ^ (rg & 3);
      const unsigned short* g = A + (arow0 + rg) * K + k0 + cg * 8;
      GLOAD_LDS16(g, &As[slot][kh][c * 8]);
    }
  };
  auto stageB = [&](int slot, int kh, int tile) {
    int k0 = tile * 64 + kh * 32;
#pragma unroll
    for (int i = 0; i < 2; ++i) {
      int c = i * 512 + wid * 64 + lane;
      int rg = c >> 2, cg = (c & 3) ^ (rg & 3);
      const unsigned short* g = Bt + (brow0 + rg) * K + k0 + cg * 8;
      GLOAD_LDS16(g, &Bs[slot][kh][c * 8]);
    }
  };

  stageA(0, 0, 0); stageB(0, 0, 0); stageA(0, 1, 0); stageB(0, 1, 0);
  stageA(1, 0, 1); stageB(1, 0, 1); stageA(1, 1, 1);
  if constexpr (BM == 256) asm volatile("s_waitcnt vmcnt(6)" ::: "memory");
  else                     asm volatile("s_waitcnt vmcnt(4)" ::: "memory");
  __builtin_amdgcn_s_barrier();

  int NT2 = K / 128;
  for (int it = 0; it < NT2; ++it) {
    int t2 = it * 2;
#pragma unroll
    for (int tt = 0; tt < 2; ++tt) {
      bf16x8 af[MR];
#pragma unroll
      for (int kh = 0; kh < 2; ++kh) {
#pragma unroll
        for (int nh = 0; nh < 2; ++nh) {
          int p = tt * 4 + kh * 2 + nh + 1;
          if (nh == 0) {
#pragma unroll
            for (int m = 0; m < MR; ++m) {
              int r = wr * (MR * 16) + m * 16 + l15;
              af[m] = ldsread128(&As[tt][kh][r * 32 + ((l4 ^ (r & 3)) * 8)]);
            }
          }
          bf16x8 bf[4];
#pragma unroll
          for (int j = 0; j < 4; ++j) {
            int r = wc * 128 + (nh * 4 + j) * 16 + l15;
            bf[j] = ldsread128(&Bs[tt][kh][r * 32 + ((l4 ^ (r & 3)) * 8)]);
          }
          if (p == 1) stageB(1, 1, t2 + 1);
          if (p == 2) stageA(0, 0, t2 + 2 <= tmax ? t2 + 2 : tmax);
          if (p == 3) stageB(0, 0, t2 + 2 <= tmax ? t2 + 2 : tmax);
          if (p == 4) stageA(0, 1, t2 + 2 <= tmax ? t2 + 2 : tmax);
          if (p == 5) stageB(0, 1, t2 + 2 <= tmax ? t2 + 2 : tmax);
          if (p == 6) stageA(1, 0, t2 + 3 <= tmax ? t2 + 3 : tmax);
          if (p == 7) stageB(1, 0, t2 + 3 <= tmax ? t2 + 3 : tmax);
          if (p == 8) stageA(1, 1, t2 + 3 <= tmax ? t2 + 3 : tmax);

          __builtin_amdgcn_s_barrier();
          asm volatile("s_waitcnt lgkmcnt(0)" ::: "memory");
          __builtin_amdgcn_sched_barrier(0);
          __builtin_amdgcn_s_setprio(1);
#pragma unroll
          for (int m = 0; m < MR; ++m)
#pragma unroll
            for (int j = 0; j < 4; ++j)
              acc[m][nh * 4 + j] = __builtin_amdgcn_mfma_f32_16x16x32_bf16(
                  af[m], bf[j], acc[m][nh * 4 + j], 0, 0, 0);
          __builtin_amdgcn_s_setprio(0);
          if (p == 4 || p == 8) {
            if constexpr (BM == 256) asm volatile("s_waitcnt vmcnt(6)" ::: "memory");
            else                     asm volatile("s_waitcnt vmcnt(4)" ::: "memory");
          }
          __builtin_amdgcn_s_barrier();
        }
      }
    }
  }

  if constexpr (QKV) {
    int cb = (int)(brow0 + wc * 128);  // wave col base, head-aligned
    if (cb >= 2560) {
      int kvh = (cb - 2560) >> 7;
#pragma unroll
      for (int m = 0; m < MR; ++m) {
        size_t row0 = arow0 + wr * (MR * 16) + m * 16 + l4 * 4;
        int bb = (int)(row0 >> 11), t0 = (int)(row0 & (T_ - 1));
#pragma unroll
        for (int n = 0; n < 8; ++n) {
          int d = n * 16 + l15;
          ushort4 p4;
          p4.x = f2bf(acc[m][n][0]);
          p4.y = f2bf(acc[m][n][1]);
          p4.z = f2bf(acc[m][n][2]);
          p4.w = f2bf(acc[m][n][3]);
          *reinterpret_cast<ushort4*>(
              vtp + (size_t)((bb * 4 + kvh) * 128 + d) * T_ + t0) = p4;
        }
      }
    } else {
#pragma unroll
      for (int m = 0; m < MR; ++m)
#pragma unroll
        for (int r = 0; r < 4; ++r) {
          size_t row = arow0 + wr * (MR * 16) + m * 16 + l4 * 4 + r;
          int t = (int)(row & (T_ - 1));
#pragma unroll
          for (int n = 0; n < 4; ++n) {
            float2 cs = rt[t * 64 + n * 16 + l15];
            float a1 = acc[m][n][r], a2 = acc[m][n + 4][r];
            size_t col = brow0 + wc * 128 + n * 16 + l15;
            Cm[row * N + col]      = f2bf(a1 * cs.x - a2 * cs.y);
            Cm[row * N + col + 64] = f2bf(a2 * cs.x + a1 * cs.y);
          }
        }
    }
  } else {
#pragma unroll
    for (int m = 0; m < MR; ++m)
#pragma unroll
      for (int r = 0; r < 4; ++r) {
        size_t row = arow0 + wr * (MR * 16) + m * 16 + l4 * 4 + r;
#pragma unroll
        for (int n = 0; n < 8; ++n) {
          size_t col = brow0 + wc * 128 + n * 16 + l15;
          Cm[row * N + col] = acc[m][n][r];
        }
      }
  }
}

// ---------------- flash attention: QBLK=256, 8 waves x 32 q-rows (512 thr),
// KVBLK=64. Same LDS (64KB) as 4-wave version but 16 waves/CU at 2 blocks/CU
// -> 4 waves/SIMD. R8 inner loop per wave. 448 blocks: qi 7..2 KV-split in
// halves (192 pairs; half-0 partial -> att in place, half-1 -> pO), qi 1,0
// unsplit. LPT dispatch order. Combine merges the 192 pairs.
__global__ __launch_bounds__(512, 2) void attn_kernel(const unsigned short* __restrict__ qkv,
                                                      const unsigned short* __restrict__ vt,
                                                      unsigned short* __restrict__ att,
                                                      unsigned short* __restrict__ pO,
                                                      float2* __restrict__ ml) {
  constexpr int KB = 64;
  __shared__ __align__(16) unsigned short Kl[2][KB * 128];   // 32KB, swizzled
  __shared__ __align__(16) unsigned short Vl[2][128 * KB];   // 32KB, swizzled
  int tid = threadIdx.x, w = tid >> 6, lane = tid & 63;
  int l31 = lane & 31, hi = lane >> 5;
  int h4 = hi * 4;

  // LPT decode: ids 0..255 = qi 7..4 splits; 256..319 qi3 splits; 320..351 qi1;
  // 352..415 qi2 splits; 416..447 qi0. (round-robin pairs long+short per CU)
  int id = blockIdx.x;
  int qi, bh, kt0, kt1, pair = -1, half = 0;
  if (id < 256) {
    qi = 7 - (id >> 6);
    int l = id & 63; bh = l >> 1; half = l & 1;
    pair = (7 - qi) * 32 + bh;
  } else if (id < 320) {
    qi = 3; int l = id - 256; bh = l >> 1; half = l & 1; pair = 128 + bh;
  } else if (id < 352) {
    qi = 1; bh = id - 320;
  } else if (id < 416) {
    qi = 2; int l = id - 352; bh = l >> 1; half = l & 1; pair = 160 + bh;
  } else {
    qi = 0; bh = id - 416;
  }
  int nt = 4 * qi + 4;
  if (pair >= 0) { int h = nt >> 1; kt0 = half ? h : 0; kt1 = half ? nt : h; }
  else           { kt0 = 0; kt1 = nt; }
  int q0 = qi * 256;
  int b = bh >> 4, hd = bh & 15, kvh = hd >> 2;
  int qr0 = q0 + w * 32;   // this wave's first q row
  int ql = qr0 + l31;      // this lane's q row

  bf16x8 qf[8];
  {
    const unsigned short* qb = qkv + (size_t)(b * T_ + ql) * NQKV_ + hd * HD_ + hi * 8;
    const float scale = 0.08838834764831845f * 1.4426950408889634f;
#pragma unroll
    for (int df = 0; df < 8; ++df) {
      bf16x8 t = *reinterpret_cast<const bf16x8*>(qb + df * 16);
#pragma unroll
      for (int j = 0; j < 8; ++j) t[j] = (__bf16)((float)t[j] * scale);
      qf[df] = t;
    }
  }

  f32x16 o[4];
#pragma unroll
  for (int dt = 0; dt < 4; ++dt)
#pragma unroll
    for (int r = 0; r < 16; ++r) o[dt][r] = 0.f;
  float mr = -1e30f, lr = 0.f;

  auto stage = [&](int buf, int kv0) {
#pragma unroll
    for (int i = 0; i < 2; ++i) {  // K tile: 1024 chunks, row = c>>4
      int c = (i * 8 + w) * 64 + lane;
      int g = c ^ ((c >> 4) & 7);
      const unsigned short* src =
          qkv + (size_t)(b * T_ + kv0 + (g >> 4)) * NQKV_ + C_ + kvh * HD_ + (g & 15) * 8;
      GLOAD_LDS16(src, &Kl[buf][(i * 8 + w) * 512]);
    }
#pragma unroll
    for (int i = 0; i < 2; ++i) {  // V^T tile: 1024 chunks, row = c>>3
      int c = (i * 8 + w) * 64 + lane;
      int g = c ^ ((c >> 3) & 7);
      const unsigned short* src =
          vt + (size_t)((b * NKV_ + kvh) * HD_ + (g >> 3)) * T_ + kv0 + (g & 7) * 8;
      GLOAD_LDS16(src, &Vl[buf][(i * 8 + w) * 512]);
    }
  };

  stage(0, kt0 * KB);
  __syncthreads();
  int cur = 0;
  for (int kt = kt0; kt < kt1; ++kt) {
    int kv0 = kt * KB;
    if (kt + 1 < kt1) stage(cur ^ 1, kv0 + KB);

    if (kv0 <= qr0 + 31) {  // wave-uniform: skip fully-masked tiles
      f32x16 s[2];
#pragma unroll
      for (int r = 0; r < 16; ++r) { s[0][r] = 0.f; s[1][r] = 0.f; }
      const unsigned short* Kb = &Kl[cur][0];
      __builtin_amdgcn_s_setprio(1);
#pragma unroll
      for (int t2 = 0; t2 < 2; ++t2)
#pragma unroll
        for (int df = 0; df < 8; ++df) {
          bf16x8 kf = *reinterpret_cast<const bf16x8*>(
              Kb + (((t2 * 32 + l31) * 128 + df * 16 + hi * 8) ^ ((l31 & 7) << 3)));
          s[t2] = __builtin_amdgcn_mfma_f32_32x32x16_bf16(kf, qf[df], s[t2], 0, 0, 0);
        }
      __builtin_amdgcn_s_setprio(0);

      float rm = -1e30f;
      if ((kv0 + KB - 1) > qr0) {
#pragma unroll
        for (int t2 = 0; t2 < 2; ++t2)
#pragma unroll
          for (int r = 0; r < 16; ++r) {
            float sv = s[t2][r];
            int kcol = kv0 + t2 * 32 + (r & 3) + 8 * (r >> 2) + h4;
            if (kcol > ql) sv = -1e30f;
            s[t2][r] = sv;
            rm = fmaxf(rm, sv);
          }
      } else {
#pragma unroll
        for (int t2 = 0; t2 < 2; ++t2)
#pragma unroll
          for (int r = 0; r < 16; ++r) rm = fmaxf(rm, s[t2][r]);
      }
      rm = fmaxf(rm, __shfl_xor(rm, 32));

      if (!__all(rm <= mr + 11.0f)) {
        float mnew = fmaxf(mr, rm);
        float alpha = exp2f(mr - mnew);
        mr = mnew;
        lr *= alpha;
#pragma unroll
        for (int dt = 0; dt < 4; ++dt)
#pragma unroll
          for (int r = 0; r < 16; ++r) o[dt][r] *= alpha;
      }

      float ps = 0.f;
#pragma unroll
      for (int t2 = 0; t2 < 2; ++t2)
#pragma unroll
        for (int r = 0; r < 16; ++r) {
          float p = exp2f(s[t2][r] - mr);
          s[t2][r] = p;
          ps += p;
        }
      lr += ps;

      unsigned pk[2][8];
#pragma unroll
      for (int t2 = 0; t2 < 2; ++t2)
#pragma unroll
        for (int i = 0; i < 8; ++i) {
          union { unsigned u32; __bf16 hh[2]; } pr;
          pr.hh[0] = (__bf16)s[t2][2 * i];
          pr.hh[1] = (__bf16)s[t2][2 * i + 1];
          pk[t2][i] = pr.u32;
        }

      bf16x8 pb[4];
#pragma unroll
      for (int f = 0; f < 4; ++f) {
        int t2 = f >> 1, bq = (f & 1) * 4;
        union { bf16x8 v; unsigned d[4]; } fr;
#pragma unroll
        for (int p = 0; p < 2; ++p) {
          unsigned uu = pk[t2][bq + p];
          unsigned ww = pk[t2][bq + 2 + p];
          unsigned us = (unsigned)__shfl_xor((int)uu, 32);
          unsigned ws = (unsigned)__shfl_xor((int)ww, 32);
          fr.d[p]     = hi ? ws : uu;
          fr.d[2 + p] = hi ? ww : us;
        }
        pb[f] = fr.v;
      }

      const unsigned short* Vb = &Vl[cur][0];
      __builtin_amdgcn_s_setprio(1);
#pragma unroll
      for (int dt = 0; dt < 4; ++dt)
#pragma unroll
        for (int kf = 0; kf < 4; ++kf) {
          bf16x8 vf = *reinterpret_cast<const bf16x8*>(
              Vb + (((dt * 32 + l31) * KB + kf * 16 + hi * 8) ^ ((l31 & 7) << 3)));
          o[dt] = __builtin_amdgcn_mfma_f32_32x32x16_bf16(vf, pb[kf], o[dt], 0, 0, 0);
        }
      __builtin_amdgcn_s_setprio(0);
    }

    __syncthreads();
    cur ^= 1;
  }

  float ls = lr + __shfl_xor(lr, 32);
  unsigned short* ob = att + (size_t)(b * T_ + ql) * C_ + hd * HD_;
  if (pair < 0) {
    float inv = 1.f / ls;
#pragma unroll
    for (int dt = 0; dt < 4; ++dt)
#pragma unroll
      for (int r = 0; r < 16; ++r) {
        int d = dt * 32 + (r & 3) + 8 * (r >> 2) + h4;
        ob[d] = f2bf(o[dt][r] * inv);
      }
  } else if (half == 0) {
    // half-0 partial: unnormalized O in att's own region
#pragma unroll
    for (int dt = 0; dt < 4; ++dt)
#pragma unroll
      for (int r = 0; r < 16; ++r) {
        int d = dt * 32 + (r & 3) + 8 * (r >> 2) + h4;
        ob[d] = f2bf(o[dt][r]);
      }
    if (hi == 0) ml[(pair * 2) * 256 + w * 32 + l31] = make_float2(mr, ls);
  } else {
    // half-1 partial: pO slot (64KB per pair)
    int lrow = w * 32 + l31;
    unsigned short* po = pO + (size_t)pair * 32768 + lrow * 128;
#pragma unroll
    for (int dt = 0; dt < 4; ++dt)
#pragma unroll
      for (int r = 0; r < 16; ++r) {
        int d = dt * 32 + (r & 3) + 8 * (r >> 2) + h4;
        po[d] = f2bf(o[dt][r]);
      }
    if (hi == 0) ml[(pair * 2 + 1) * 256 + lrow] = make_float2(mr, ls);
  }
}

// ---------------- merge KV-split halves in place:
// att (half0, unnormalized) + pO (half1) -> att = (w0*O0 + w1*O1)/(w0*l0+w1*l1)
__global__ void combine_kernel(const unsigned short* __restrict__ pO,
                               const float2* __restrict__ ml,
                               unsigned short* __restrict__ att) {
  int pair = blockIdx.x;               // 0..191
  int qi, bh;
  if (pair < 128)      { qi = 7 - (pair >> 5); bh = pair & 31; }
  else if (pair < 160) { qi = 3; bh = pair - 128; }
  else                 { qi = 2; bh = pair - 160; }
  int b = bh >> 4, hd = bh & 15;
  int q0 = qi * 256;
  int tid = threadIdx.x;               // 256: 8 threads per row, 16 shorts each
#pragma unroll
  for (int it = 0; it < 8; ++it) {
    int row = it * 32 + (tid >> 3);
    int cb = (tid & 7) * 16;
    float2 ml0 = ml[(pair * 2) * 256 + row], ml1 = ml[(pair * 2 + 1) * 256 + row];
    float m = fmaxf(ml0.x, ml1.x);
    float w0 = exp2f(ml0.x - m), w1 = exp2f(ml1.x - m);
    float inv = 1.f / (w0 * ml0.y + w1 * ml1.y);
    unsigned short* ob = att + (size_t)(b * T_ + q0 + row) * C_ + hd * HD_ + cb;
    const unsigned short* p1 = pO + (size_t)pair * 32768 + row * 128 + cb;
#pragma unroll
    for (int j = 0; j < 16; j += 4) {
      ushort4 a = *reinterpret_cast<const ushort4*>(ob + j);
      ushort4 c = *reinterpret_cast<const ushort4*>(p1 + j);
      ushort4 r;
      r.x = f2bf((w0 * bf2f(a.x) + w1 * bf2f(c.x)) * inv);
      r.y = f2bf((w0 * bf2f(a.y) + w1 * bf2f(c.y)) * inv);
      r.z = f2bf((w0 * bf2f(a.z) + w1 * bf2f(c.z)) * inv);
      r.w = f2bf((w0 * bf2f(a.w) + w1 * bf2f(c.w)) * inv);
      *reinterpret_cast<ushort4*>(ob + j) = r;
    }
  }
}

extern "C" void kernel_launch(void* const* d_in, const int* in_sizes, int n_in,
                              void* d_out, int out_size, void* d_ws, size_t ws_size,
                              hipStream_t stream) {
  const float* x  = (const float*)d_in[0];
  const float* Wq = (const float*)d_in[1];
  const float* Wk = (const float*)d_in[2];
  const float* Wv = (const float*)d_in[3];
  const float* Wp = (const float*)d_in[4];
  float* out = (float*)d_out;
  char* ws = (char*)d_ws;

  // workspace layout (bytes); total 68,157,440
  unsigned short* xb  = (unsigned short*)(ws);              // 16MB  x bf16 (att aliases)
  unsigned short* wt  = (unsigned short*)(ws + 16777216);   // 20MB  Wq^T|Wk^T|Wv^T|Wp^T
  unsigned short* qkv = (unsigned short*)(ws + 37748736);   // 24MB  q(rope)|k(rope)
  float2*         rt  = (float2*)(ws + 62914560);           // 1MB   cos/sin (dead after GEMM1)
  unsigned short* vt  = (unsigned short*)(ws + 63963136);   // 4MB   V d-major [bh*HD+d][t]
  unsigned short* att = xb;                                 // alias: xb dead after GEMM1
  unsigned short* pO  = wt;                                 // alias: 192 x 64KB = 12.58MB exactly
  float2*         ml  = rt;                                 // alias: 384 x 256 x 8B = 768KB

  prep_kernel<<<dim3(11264), 256, 0, stream>>>(x, Wq, Wk, Wv, Wp, xb, wt, rt);

  gemm8p<256, unsigned short, true><<<dim3(NQKV_ / 256, M_ / 256), 512, 0, stream>>>(
      xb, wt, qkv, vt, rt, M_, NQKV_, C_);
  attn_kernel<<<dim3(448), 512, 0, stream>>>(qkv, vt, att, pO, ml);
  combine_kernel<<<dim3(192), 256, 0, stream>>>(pO, ml, att);
  gemm8p<128, float, false><<<dim3(C_ / 256, M_ / 128), 512, 0, stream>>>(
      att, wt + (size_t)3072 * 2048, out, nullptr, nullptr, M_, C_, C_);
}

// Round 23
// 206.973 us; speedup vs baseline: 1.3650x; 1.0152x over previous
//
#include <hip/hip_runtime.h>

#define B_ 2
#define T_ 2048
#define C_ 2048
#define NH_ 16
#define NKV_ 4
#define HD_ 128
#define M_ 4096          // B*T
#define NQKV_ 3072

typedef __bf16 bf16x8 __attribute__((ext_vector_type(8)));
typedef float f32x4 __attribute__((ext_vector_type(4)));
typedef float f32x16 __attribute__((ext_vector_type(16)));

__device__ __forceinline__ unsigned short f2bf(float f) {
  union { float f; unsigned u; } c{f};
  unsigned u = c.u + 0x7FFFu + ((c.u >> 16) & 1u);
  return (unsigned short)(u >> 16);
}
__device__ __forceinline__ float bf2f(unsigned short h) {
  union { unsigned u; float f; } c{(unsigned)h << 16};
  return c.f;
}

#define GLOAD_LDS16(g, l)                                        \
  __builtin_amdgcn_global_load_lds(                              \
      (const __attribute__((address_space(1))) void*)(g),        \
      (__attribute__((address_space(3))) void*)(l), 16, 0, 0)

// asm ds_read_b128 (rule #18: fence with lgkmcnt(0)+sched_barrier(0) before use)
__device__ __forceinline__ bf16x8 ldsread128(const unsigned short* p) {
  uint4 d;
  asm volatile("ds_read_b128 %0, %1"
               : "=v"(d)
               : "v"((const __attribute__((address_space(3))) void*)p));
  union { uint4 u; bf16x8 v; } c;
  c.u = d;
  return c.v;
}

// ---------------- fused prep: weight transposes (64x64 tiles) + x->bf16 + rope
__global__ void prep_kernel(const float* __restrict__ x, const float* __restrict__ Wq,
                            const float* __restrict__ Wk, const float* __restrict__ Wv,
                            const float* __restrict__ Wp, unsigned short* __restrict__ xb,
                            unsigned short* __restrict__ wt, float2* __restrict__ rt) {
  int id = blockIdx.x;
  int t = threadIdx.x;
  if (id < 2560) {  // weight transpose-convert, 64x64 tile
    __shared__ float tile[64][65];
    const float* W;
    unsigned short* Wt;
    int N, bx, by;
    if (id < 1024)      { W = Wq; Wt = wt;                       N = 2048; int u = id;        bx = u & 31; by = u >> 5; }
    else if (id < 1280) { W = Wk; Wt = wt + (size_t)2048 * 2048; N = 512;  int u = id - 1024; bx = u & 7;  by = u >> 3; }
    else if (id < 1536) { W = Wv; Wt = wt + (size_t)2560 * 2048; N = 512;  int u = id - 1280; bx = u & 7;  by = u >> 3; }
    else                { W = Wp; Wt = wt + (size_t)3072 * 2048; N = 2048; int u = id - 1536; bx = u & 31; by = u >> 5; }
    const int K = 2048;
    bx *= 64; by *= 64;
    int n = t & 63, k4 = t >> 6;
#pragma unroll
    for (int r = 0; r < 16; ++r)
      tile[k4 + r * 4][n] = W[(size_t)(by + k4 + r * 4) * N + bx + n];
    __syncthreads();
    int nw = t >> 2, kb = (t & 3) * 16;
    unsigned short tmp[16];
#pragma unroll
    for (int j = 0; j < 16; ++j) tmp[j] = f2bf(tile[kb + j][nw]);
    unsigned short* dst = Wt + (size_t)(bx + nw) * K + by + kb;
#pragma unroll
    for (int j = 0; j < 2; ++j)
      *reinterpret_cast<uint4*>(dst + j * 8) = reinterpret_cast<uint4*>(tmp)[j];
  } else if (id < 10752) {  // x f32 -> bf16
    int i = (id - 2560) * 256 + t;
    float4 v = reinterpret_cast<const float4*>(x)[i];
    union { ushort4 u; unsigned short s[4]; } o;
    o.s[0] = f2bf(v.x); o.s[1] = f2bf(v.y); o.s[2] = f2bf(v.z); o.s[3] = f2bf(v.w);
    reinterpret_cast<ushort4*>(xb)[i] = o.u;
  } else {  // rope table
    int g = (id - 10752) * 256 + t;
    int tt = g >> 6, i = g & 63;
    float inv = powf(10000.f, -(float)(2 * i) / 128.f);
    float s, c;
    sincosf((float)tt * inv, &s, &c);
    rt[tt * 64 + i] = make_float2(c, s);
  }
}

// ---------------- 8-phase bf16 GEMM (T3+T4+T5), asm ds_read (R14, proven).
// QKV=true epilogue: q,k -> rope -> qkv; V head-blocks -> vt d-major directly.
template <int BM, typename OUT, bool QKV>
__global__ __launch_bounds__(512, 1) void gemm8p(const unsigned short* __restrict__ A,
                                                 const unsigned short* __restrict__ Bt,
                                                 OUT* __restrict__ Cm,
                                                 unsigned short* __restrict__ vtp,
                                                 const float2* __restrict__ rt,
                                                 int M, int N, int K) {
  constexpr int MR = BM / 64;
  __shared__ __align__(16) unsigned short As[2][2][BM * 32];
  __shared__ __align__(16) unsigned short Bs[2][2][256 * 32];
  int tid = threadIdx.x, wid = tid >> 6, lane = tid & 63;
  int l15 = lane & 15, l4 = lane >> 4;
  int wr = wid >> 1, wc = wid & 1;
  size_t arow0 = (size_t)blockIdx.y * BM;
  size_t brow0 = (size_t)blockIdx.x * 256;
  int tmax = K / 64 - 1;

  f32x4 acc[MR][8];
#pragma unroll
  for (int m = 0; m < MR; ++m)
#pragma unroll
    for (int n = 0; n < 8; ++n) acc[m][n] = (f32x4){0.f, 0.f, 0.f, 0.f};

  auto stageA = [&](int slot, int kh, int tile) {
    int k0 = tile * 64 + kh * 32;
    constexpr int NLD = (BM * 32 * 2) / (512 * 16);
#pragma unroll
    for (int i = 0; i < NLD; ++i) {
      int c = i * 512 + wid * 64 + lane;
      int rg = c >> 2, cg = (c & 3) ^ (rg & 3);
      const unsigned short* g = A + (arow0 + rg) * K + k0 + cg * 8;
      GLOAD_LDS16(g, &As[slot][kh][c * 8]);
    }
  };
  auto stageB = [&](int slot, int kh, int tile) {
    int k0 = tile * 64 + kh * 32;
#pragma unroll
    for (int i = 0; i < 2; ++i) {
      int c = i * 512 + wid * 64 + lane;
      int rg = c >> 2, cg = (c & 3) ^ (rg & 3);
      const unsigned short* g = Bt + (brow0 + rg) * K + k0 + cg * 8;
      GLOAD_LDS16(g, &Bs[slot][kh][c * 8]);
    }
  };

  stageA(0, 0, 0); stageB(0, 0, 0); stageA(0, 1, 0); stageB(0, 1, 0);
  stageA(1, 0, 1); stageB(1, 0, 1); stageA(1, 1, 1);
  if constexpr (BM == 256) asm volatile("s_waitcnt vmcnt(6)" ::: "memory");
  else                     asm volatile("s_waitcnt vmcnt(4)" ::: "memory");
  __builtin_amdgcn_s_barrier();

  int NT2 = K / 128;
  for (int it = 0; it < NT2; ++it) {
    int t2 = it * 2;
#pragma unroll
    for (int tt = 0; tt < 2; ++tt) {
      bf16x8 af[MR];
#pragma unroll
      for (int kh = 0; kh < 2; ++kh) {
#pragma unroll
        for (int nh = 0; nh < 2; ++nh) {
          int p = tt * 4 + kh * 2 + nh + 1;
          if (nh == 0) {
#pragma unroll
            for (int m = 0; m < MR; ++m) {
              int r = wr * (MR * 16) + m * 16 + l15;
              af[m] = ldsread128(&As[tt][kh][r * 32 + ((l4 ^ (r & 3)) * 8)]);
            }
          }
          bf16x8 bf[4];
#pragma unroll
          for (int j = 0; j < 4; ++j) {
            int r = wc * 128 + (nh * 4 + j) * 16 + l15;
            bf[j] = ldsread128(&Bs[tt][kh][r * 32 + ((l4 ^ (r & 3)) * 8)]);
          }
          if (p == 1) stageB(1, 1, t2 + 1);
          if (p == 2) stageA(0, 0, t2 + 2 <= tmax ? t2 + 2 : tmax);
          if (p == 3) stageB(0, 0, t2 + 2 <= tmax ? t2 + 2 : tmax);
          if (p == 4) stageA(0, 1, t2 + 2 <= tmax ? t2 + 2 : tmax);
          if (p == 5) stageB(0, 1, t2 + 2 <= tmax ? t2 + 2 : tmax);
          if (p == 6) stageA(1, 0, t2 + 3 <= tmax ? t2 + 3 : tmax);
          if (p == 7) stageB(1, 0, t2 + 3 <= tmax ? t2 + 3 : tmax);
          if (p == 8) stageA(1, 1, t2 + 3 <= tmax ? t2 + 3 : tmax);

          __builtin_amdgcn_s_barrier();
          asm volatile("s_waitcnt lgkmcnt(0)" ::: "memory");
          __builtin_amdgcn_sched_barrier(0);
          __builtin_amdgcn_s_setprio(1);
#pragma unroll
          for (int m = 0; m < MR; ++m)
#pragma unroll
            for (int j = 0; j < 4; ++j)
              acc[m][nh * 4 + j] = __builtin_amdgcn_mfma_f32_16x16x32_bf16(
                  af[m], bf[j], acc[m][nh * 4 + j], 0, 0, 0);
          __builtin_amdgcn_s_setprio(0);
          if (p == 4 || p == 8) {
            if constexpr (BM == 256) asm volatile("s_waitcnt vmcnt(6)" ::: "memory");
            else                     asm volatile("s_waitcnt vmcnt(4)" ::: "memory");
          }
          __builtin_amdgcn_s_barrier();
        }
      }
    }
  }

  if constexpr (QKV) {
    int cb = (int)(brow0 + wc * 128);  // wave col base, head-aligned
    if (cb >= 2560) {
      int kvh = (cb - 2560) >> 7;
#pragma unroll
      for (int m = 0; m < MR; ++m) {
        size_t row0 = arow0 + wr * (MR * 16) + m * 16 + l4 * 4;
        int bb = (int)(row0 >> 11), t0 = (int)(row0 & (T_ - 1));
#pragma unroll
        for (int n = 0; n < 8; ++n) {
          int d = n * 16 + l15;
          ushort4 p4;
          p4.x = f2bf(acc[m][n][0]);
          p4.y = f2bf(acc[m][n][1]);
          p4.z = f2bf(acc[m][n][2]);
          p4.w = f2bf(acc[m][n][3]);
          *reinterpret_cast<ushort4*>(
              vtp + (size_t)((bb * 4 + kvh) * 128 + d) * T_ + t0) = p4;
        }
      }
    } else {
#pragma unroll
      for (int m = 0; m < MR; ++m)
#pragma unroll
        for (int r = 0; r < 4; ++r) {
          size_t row = arow0 + wr * (MR * 16) + m * 16 + l4 * 4 + r;
          int t = (int)(row & (T_ - 1));
#pragma unroll
          for (int n = 0; n < 4; ++n) {
            float2 cs = rt[t * 64 + n * 16 + l15];
            float a1 = acc[m][n][r], a2 = acc[m][n + 4][r];
            size_t col = brow0 + wc * 128 + n * 16 + l15;
            Cm[row * N + col]      = f2bf(a1 * cs.x - a2 * cs.y);
            Cm[row * N + col + 64] = f2bf(a2 * cs.x + a1 * cs.y);
          }
        }
    }
  } else {
#pragma unroll
    for (int m = 0; m < MR; ++m)
#pragma unroll
      for (int r = 0; r < 4; ++r) {
        size_t row = arow0 + wr * (MR * 16) + m * 16 + l4 * 4 + r;
#pragma unroll
        for (int n = 0; n < 8; ++n) {
          size_t col = brow0 + wc * 128 + n * 16 + l15;
          Cm[row * N + col] = acc[m][n][r];
        }
      }
  }
}

// ---------------- flash attention: QBLK=256, 8 waves x 32 q-rows (512 thr),
// KVBLK=64, R8 inner loop per wave, KV-split LPT grid (R22). P^T exchange via
// v_permlane32_swap_b32 (T12; replaces 16 ds_bpermute + 16 selects with 8 VALU
// ops — mapping identical to R9-validated implementation).
__global__ __launch_bounds__(512, 2) void attn_kernel(const unsigned short* __restrict__ qkv,
                                                      const unsigned short* __restrict__ vt,
                                                      unsigned short* __restrict__ att,
                                                      unsigned short* __restrict__ pO,
                                                      float2* __restrict__ ml) {
  constexpr int KB = 64;
  __shared__ __align__(16) unsigned short Kl[2][KB * 128];   // 32KB, swizzled
  __shared__ __align__(16) unsigned short Vl[2][128 * KB];   // 32KB, swizzled
  int tid = threadIdx.x, w = tid >> 6, lane = tid & 63;
  int l31 = lane & 31, hi = lane >> 5;
  int h4 = hi * 4;

  // LPT decode: ids 0..255 = qi 7..4 splits; 256..319 qi3 splits; 320..351 qi1;
  // 352..415 qi2 splits; 416..447 qi0. (round-robin pairs long+short per CU)
  int id = blockIdx.x;
  int qi, bh, kt0, kt1, pair = -1, half = 0;
  if (id < 256) {
    qi = 7 - (id >> 6);
    int l = id & 63; bh = l >> 1; half = l & 1;
    pair = (7 - qi) * 32 + bh;
  } else if (id < 320) {
    qi = 3; int l = id - 256; bh = l >> 1; half = l & 1; pair = 128 + bh;
  } else if (id < 352) {
    qi = 1; bh = id - 320;
  } else if (id < 416) {
    qi = 2; int l = id - 352; bh = l >> 1; half = l & 1; pair = 160 + bh;
  } else {
    qi = 0; bh = id - 416;
  }
  int nt = 4 * qi + 4;
  if (pair >= 0) { int h = nt >> 1; kt0 = half ? h : 0; kt1 = half ? nt : h; }
  else           { kt0 = 0; kt1 = nt; }
  int q0 = qi * 256;
  int b = bh >> 4, hd = bh & 15, kvh = hd >> 2;
  int qr0 = q0 + w * 32;   // this wave's first q row
  int ql = qr0 + l31;      // this lane's q row

  bf16x8 qf[8];
  {
    const unsigned short* qb = qkv + (size_t)(b * T_ + ql) * NQKV_ + hd * HD_ + hi * 8;
    const float scale = 0.08838834764831845f * 1.4426950408889634f;
#pragma unroll
    for (int df = 0; df < 8; ++df) {
      bf16x8 t = *reinterpret_cast<const bf16x8*>(qb + df * 16);
#pragma unroll
      for (int j = 0; j < 8; ++j) t[j] = (__bf16)((float)t[j] * scale);
      qf[df] = t;
    }
  }

  f32x16 o[4];
#pragma unroll
  for (int dt = 0; dt < 4; ++dt)
#pragma unroll
    for (int r = 0; r < 16; ++r) o[dt][r] = 0.f;
  float mr = -1e30f, lr = 0.f;

  auto stage = [&](int buf, int kv0) {
#pragma unroll
    for (int i = 0; i < 2; ++i) {  // K tile: 1024 chunks, row = c>>4
      int c = (i * 8 + w) * 64 + lane;
      int g = c ^ ((c >> 4) & 7);
      const unsigned short* src =
          qkv + (size_t)(b * T_ + kv0 + (g >> 4)) * NQKV_ + C_ + kvh * HD_ + (g & 15) * 8;
      GLOAD_LDS16(src, &Kl[buf][(i * 8 + w) * 512]);
    }
#pragma unroll
    for (int i = 0; i < 2; ++i) {  // V^T tile: 1024 chunks, row = c>>3
      int c = (i * 8 + w) * 64 + lane;
      int g = c ^ ((c >> 3) & 7);
      const unsigned short* src =
          vt + (size_t)((b * NKV_ + kvh) * HD_ + (g >> 3)) * T_ + kv0 + (g & 7) * 8;
      GLOAD_LDS16(src, &Vl[buf][(i * 8 + w) * 512]);
    }
  };

  stage(0, kt0 * KB);
  __syncthreads();
  int cur = 0;
  for (int kt = kt0; kt < kt1; ++kt) {
    int kv0 = kt * KB;
    if (kt + 1 < kt1) stage(cur ^ 1, kv0 + KB);

    if (kv0 <= qr0 + 31) {  // wave-uniform: skip fully-masked tiles
      f32x16 s[2];
#pragma unroll
      for (int r = 0; r < 16; ++r) { s[0][r] = 0.f; s[1][r] = 0.f; }
      const unsigned short* Kb = &Kl[cur][0];
      __builtin_amdgcn_s_setprio(1);
#pragma unroll
      for (int t2 = 0; t2 < 2; ++t2)
#pragma unroll
        for (int df = 0; df < 8; ++df) {
          bf16x8 kf = *reinterpret_cast<const bf16x8*>(
              Kb + (((t2 * 32 + l31) * 128 + df * 16 + hi * 8) ^ ((l31 & 7) << 3)));
          s[t2] = __builtin_amdgcn_mfma_f32_32x32x16_bf16(kf, qf[df], s[t2], 0, 0, 0);
        }
      __builtin_amdgcn_s_setprio(0);

      float rm = -1e30f;
      if ((kv0 + KB - 1) > qr0) {
#pragma unroll
        for (int t2 = 0; t2 < 2; ++t2)
#pragma unroll
          for (int r = 0; r < 16; ++r) {
            float sv = s[t2][r];
            int kcol = kv0 + t2 * 32 + (r & 3) + 8 * (r >> 2) + h4;
            if (kcol > ql) sv = -1e30f;
            s[t2][r] = sv;
            rm = fmaxf(rm, sv);
          }
      } else {
#pragma unroll
        for (int t2 = 0; t2 < 2; ++t2)
#pragma unroll
          for (int r = 0; r < 16; ++r) rm = fmaxf(rm, s[t2][r]);
      }
      rm = fmaxf(rm, __shfl_xor(rm, 32));

      if (!__all(rm <= mr + 11.0f)) {
        float mnew = fmaxf(mr, rm);
        float alpha = exp2f(mr - mnew);
        mr = mnew;
        lr *= alpha;
#pragma unroll
        for (int dt = 0; dt < 4; ++dt)
#pragma unroll
          for (int r = 0; r < 16; ++r) o[dt][r] *= alpha;
      }

      float ps = 0.f;
#pragma unroll
      for (int t2 = 0; t2 < 2; ++t2)
#pragma unroll
        for (int r = 0; r < 16; ++r) {
          float p = exp2f(s[t2][r] - mr);
          s[t2][r] = p;
          ps += p;
        }
      lr += ps;

      unsigned pk[2][8];
#pragma unroll
      for (int t2 = 0; t2 < 2; ++t2)
#pragma unroll
        for (int i = 0; i < 8; ++i) {
          union { unsigned u32; __bf16 hh[2]; } pr;
          pr.hh[0] = (__bf16)s[t2][2 * i];
          pr.hh[1] = (__bf16)s[t2][2 * i + 1];
          pk[t2][i] = pr.u32;
        }

      // P^T B-frags via permlane32_swap: a <- {uu_lo, ww_lo}, b <- {uu_hi, ww_hi}
      bf16x8 pb[4];
#pragma unroll
      for (int f = 0; f < 4; ++f) {
        int t2 = f >> 1, bq = (f & 1) * 4;
        union { bf16x8 v; unsigned d[4]; } fr;
#pragma unroll
        for (int p = 0; p < 2; ++p) {
          unsigned a = pk[t2][bq + p];
          unsigned bb2 = pk[t2][bq + 2 + p];
          asm("v_permlane32_swap_b32 %0, %1" : "+v"(a), "+v"(bb2));
          fr.d[p] = a;
          fr.d[2 + p] = bb2;
        }
        pb[f] = fr.v;
      }

      const unsigned short* Vb = &Vl[cur][0];
      __builtin_amdgcn_s_setprio(1);
#pragma unroll
      for (int dt = 0; dt < 4; ++dt)
#pragma unroll
        for (int kf = 0; kf < 4; ++kf) {
          bf16x8 vf = *reinterpret_cast<const bf16x8*>(
              Vb + (((dt * 32 + l31) * KB + kf * 16 + hi * 8) ^ ((l31 & 7) << 3)));
          o[dt] = __builtin_amdgcn_mfma_f32_32x32x16_bf16(vf, pb[kf], o[dt], 0, 0, 0);
        }
      __builtin_amdgcn_s_setprio(0);
    }

    __syncthreads();
    cur ^= 1;
  }

  float ls = lr + __shfl_xor(lr, 32);
  unsigned short* ob = att + (size_t)(b * T_ + ql) * C_ + hd * HD_;
  if (pair < 0) {
    float inv = 1.f / ls;
#pragma unroll
    for (int dt = 0; dt < 4; ++dt)
#pragma unroll
      for (int r = 0; r < 16; ++r) {
        int d = dt * 32 + (r & 3) + 8 * (r >> 2) + h4;
        ob[d] = f2bf(o[dt][r] * inv);
      }
  } else if (half == 0) {
    // half-0 partial: unnormalized O in att's own region
#pragma unroll
    for (int dt = 0; dt < 4; ++dt)
#pragma unroll
      for (int r = 0; r < 16; ++r) {
        int d = dt * 32 + (r & 3) + 8 * (r >> 2) + h4;
        ob[d] = f2bf(o[dt][r]);
      }
    if (hi == 0) ml[(pair * 2) * 256 + w * 32 + l31] = make_float2(mr, ls);
  } else {
    // half-1 partial: pO slot (64KB per pair)
    int lrow = w * 32 + l31;
    unsigned short* po = pO + (size_t)pair * 32768 + lrow * 128;
#pragma unroll
    for (int dt = 0; dt < 4; ++dt)
#pragma unroll
      for (int r = 0; r < 16; ++r) {
        int d = dt * 32 + (r & 3) + 8 * (r >> 2) + h4;
        po[d] = f2bf(o[dt][r]);
      }
    if (hi == 0) ml[(pair * 2 + 1) * 256 + lrow] = make_float2(mr, ls);
  }
}

// ---------------- merge KV-split halves in place:
// att (half0, unnormalized) + pO (half1) -> att = (w0*O0 + w1*O1)/(w0*l0+w1*l1)
__global__ void combine_kernel(const unsigned short* __restrict__ pO,
                               const float2* __restrict__ ml,
                               unsigned short* __restrict__ att) {
  int pair = blockIdx.x;               // 0..191
  int qi, bh;
  if (pair < 128)      { qi = 7 - (pair >> 5); bh = pair & 31; }
  else if (pair < 160) { qi = 3; bh = pair - 128; }
  else                 { qi = 2; bh = pair - 160; }
  int b = bh >> 4, hd = bh & 15;
  int q0 = qi * 256;
  int tid = threadIdx.x;               // 256: 8 threads per row, 16 shorts each
#pragma unroll
  for (int it = 0; it < 8; ++it) {
    int row = it * 32 + (tid >> 3);
    int cb = (tid & 7) * 16;
    float2 ml0 = ml[(pair * 2) * 256 + row], ml1 = ml[(pair * 2 + 1) * 256 + row];
    float m = fmaxf(ml0.x, ml1.x);
    float w0 = exp2f(ml0.x - m), w1 = exp2f(ml1.x - m);
    float inv = 1.f / (w0 * ml0.y + w1 * ml1.y);
    unsigned short* ob = att + (size_t)(b * T_ + q0 + row) * C_ + hd * HD_ + cb;
    const unsigned short* p1 = pO + (size_t)pair * 32768 + row * 128 + cb;
#pragma unroll
    for (int j = 0; j < 16; j += 4) {
      ushort4 a = *reinterpret_cast<const ushort4*>(ob + j);
      ushort4 c = *reinterpret_cast<const ushort4*>(p1 + j);
      ushort4 r;
      r.x = f2bf((w0 * bf2f(a.x) + w1 * bf2f(c.x)) * inv);
      r.y = f2bf((w0 * bf2f(a.y) + w1 * bf2f(c.y)) * inv);
      r.z = f2bf((w0 * bf2f(a.z) + w1 * bf2f(c.z)) * inv);
      r.w = f2bf((w0 * bf2f(a.w) + w1 * bf2f(c.w)) * inv);
      *reinterpret_cast<ushort4*>(ob + j) = r;
    }
  }
}

extern "C" void kernel_launch(void* const* d_in, const int* in_sizes, int n_in,
                              void* d_out, int out_size, void* d_ws, size_t ws_size,
                              hipStream_t stream) {
  const float* x  = (const float*)d_in[0];
  const float* Wq = (const float*)d_in[1];
  const float* Wk = (const float*)d_in[2];
  const float* Wv = (const float*)d_in[3];
  const float* Wp = (const float*)d_in[4];
  float* out = (float*)d_out;
  char* ws = (char*)d_ws;

  // workspace layout (bytes); total 68,157,440
  unsigned short* xb  = (unsigned short*)(ws);              // 16MB  x bf16 (att aliases)
  unsigned short* wt  = (unsigned short*)(ws + 16777216);   // 20MB  Wq^T|Wk^T|Wv^T|Wp^T
  unsigned short* qkv = (unsigned short*)(ws + 37748736);   // 24MB  q(rope)|k(rope)
  float2*         rt  = (float2*)(ws + 62914560);           // 1MB   cos/sin (dead after GEMM1)
  unsigned short* vt  = (unsigned short*)(ws + 63963136);   // 4MB   V d-major [bh*HD+d][t]
  unsigned short* att = xb;                                 // alias: xb dead after GEMM1
  unsigned short* pO  = wt;                                 // alias: 192 x 64KB = 12.58MB exactly
  float2*         ml  = rt;                                 // alias: 384 x 256 x 8B = 768KB

  prep_kernel<<<dim3(11264), 256, 0, stream>>>(x, Wq, Wk, Wv, Wp, xb, wt, rt);

  gemm8p<256, unsigned short, true><<<dim3(NQKV_ / 256, M_ / 256), 512, 0, stream>>>(
      xb, wt, qkv, vt, rt, M_, NQKV_, C_);
  attn_kernel<<<dim3(448), 512, 0, stream>>>(qkv, vt, att, pO, ml);
  combine_kernel<<<dim3(192), 256, 0, stream>>>(pO, ml, att);
  gemm8p<128, float, false><<<dim3(C_ / 256, M_ / 128), 512, 0, stream>>>(
      att, wt + (size_t)3072 * 2048, out, nullptr, nullptr, M_, C_, C_);
}